// Round 10
// baseline (1046.778 us; speedup 1.0000x reference)
//
#include <hip/hip_runtime.h>

#define HIDDEN 128
#define ZDIM 56
#define NLAYERS 3
#define NGRAPHS 1024

typedef __attribute__((ext_vector_type(8))) short short8v;
typedef __attribute__((ext_vector_type(4))) float float4v;

__device__ __forceinline__ ushort f2bf(float v) {
    union { float f; unsigned u; } x; x.f = v;
    unsigned r = x.u + 0x7fffu + ((x.u >> 16) & 1u);   // RNE
    return (ushort)(r >> 16);
}
__device__ __forceinline__ float bf2f(ushort h) {
    union { unsigned u; float f; } x; x.u = ((unsigned)h) << 16;
    return x.f;
}
__device__ __forceinline__ void split_bf(float v, ushort& hi, ushort& lo) {
    hi = f2bf(v);
    lo = f2bf(v - bf2f(hi));
}

// ============ split-bf16 MFMA GEMM: C[n x TN] = act(X[n x 128] @ W[128 x TN] (+bias)) ============
// X as hi/lo bf16 planes [n][128]; W TRANSPOSED as hi/lo [TN][128].
// NO LDS, NO BARRIERS: both operands are fetched directly global->VGPR as the exact
// 16B MFMA fragments.
//   A-frag (X): lane l reads rows {wr*64+i*16+(l&15)}, k-bytes [(l>>4)*16 +16); a wave
//     covers 16 rows x 64B contiguous (stride 256B) -> X read exactly once from HBM.
//   B-frag (W): lane l reads WT[col][k] 16B; W is 128KB/layer -> L2-resident across all
//     blocks, re-reads are L2 hits.
// Block 512 thr / 8 waves; tile M=128. Wave w: row-half wr=w>>2, col group wc=w&3.
// 3 MFMAs per (hi,lo) pair: ah*bh + ah*bl + al*bh  (al*bl ~2^-18, dropped).
// Same MFMA order as the verified R7 kernel -> numerics identical.
template<int TN, bool RELU, bool BIAS, bool OUTHILO>
__global__ __launch_bounds__(512, 4)
void gemm_mfma(const ushort* __restrict__ Xhi, const ushort* __restrict__ Xlo,
               const ushort* __restrict__ WThi, const ushort* __restrict__ WTlo,
               const float* __restrict__ bias,
               float* __restrict__ Cf, ushort* __restrict__ Chi, ushort* __restrict__ Clo,
               int n)
{
    constexpr int K = 128;
    constexpr int CPW = TN / 64;            // col frags per wave
    const int tid = threadIdx.x;
    const int w = tid >> 6, l = tid & 63;
    const int wr = w >> 2;                  // row half
    const int wc = w & 3;                   // col group
    const int seg = l >> 4, lr = l & 15;
    const int row0 = blockIdx.x * 128;
    if (row0 >= n) return;

    // A-frag row addresses (clamped for tail tiles; OOB rows never stored)
    size_t aoff[4];
#pragma unroll
    for (int i = 0; i < 4; ++i) {
        int r = row0 + wr * 64 + i * 16 + lr;
        if (r > n - 1) r = n - 1;
        aoff[i] = (size_t)r * K + seg * 8;
    }
    size_t boff[CPW];
#pragma unroll
    for (int j = 0; j < CPW; ++j) {
        const int col = (wc * CPW + j) * 16 + lr;
        boff[j] = (size_t)col * K + seg * 8;
    }

    float4v acc[4][CPW];
#pragma unroll
    for (int i = 0; i < 4; ++i)
#pragma unroll
        for (int j = 0; j < CPW; ++j) {
            float4v z = {0.f, 0.f, 0.f, 0.f};
            acc[i][j] = z;
        }

#pragma unroll
    for (int kc = 0; kc < K; kc += 32) {
        short8v ah[4], al[4];
#pragma unroll
        for (int i = 0; i < 4; ++i) {
            ah[i] = *(const short8v*)&Xhi[aoff[i] + kc];
            al[i] = *(const short8v*)&Xlo[aoff[i] + kc];
        }
#pragma unroll
        for (int j = 0; j < CPW; ++j) {
            short8v bh = *(const short8v*)&WThi[boff[j] + kc];
            short8v bl = *(const short8v*)&WTlo[boff[j] + kc];
#pragma unroll
            for (int i = 0; i < 4; ++i) {
                acc[i][j] = __builtin_amdgcn_mfma_f32_16x16x32_bf16(ah[i], bh, acc[i][j], 0, 0, 0);
                acc[i][j] = __builtin_amdgcn_mfma_f32_16x16x32_bf16(ah[i], bl, acc[i][j], 0, 0, 0);
                acc[i][j] = __builtin_amdgcn_mfma_f32_16x16x32_bf16(al[i], bh, acc[i][j], 0, 0, 0);
            }
        }
    }

    // epilogue: D[row = seg*4 + r, col = lr] within each 16x16 frag (R7-style direct stores)
#pragma unroll
    for (int i = 0; i < 4; ++i) {
#pragma unroll
        for (int j = 0; j < CPW; ++j) {
            const int gcol = (wc * CPW + j) * 16 + lr;
            const float bv = BIAS ? bias[gcol] : 0.f;
#pragma unroll
            for (int r = 0; r < 4; ++r) {
                const int grow = row0 + wr * 64 + i * 16 + seg * 4 + r;
                if (grow < n) {
                    float v = acc[i][j][r] + bv;
                    if (RELU) v = fmaxf(v, 0.f);
                    if (OUTHILO) {
                        ushort hi, lo;
                        split_bf(v, hi, lo);
                        Chi[(size_t)grow * TN + gcol] = hi;
                        Clo[(size_t)grow * TN + gcol] = lo;
                    } else {
                        Cf[(size_t)grow * TN + gcol] = v;
                    }
                }
            }
        }
    }
}

// ============ f32 vector GEMM for input projection (K=32/64), TN=128 ============
template<int K, bool OUTHILO>
__global__ __launch_bounds__(256)
void gemm_rt(const float* __restrict__ X, const float* __restrict__ W,
             const float* __restrict__ bias, float* __restrict__ Cf,
             ushort* __restrict__ Chi, ushort* __restrict__ Clo, int n)
{
    constexpr int TN = 128;
    constexpr int KC = 32;
    __shared__ float sXT[KC][128];
    __shared__ float sW[KC][TN];

    const int tid  = threadIdx.x;
    const int row0 = blockIdx.x * 128;
    const int rows = min(128, n - row0);
    if (rows <= 0) return;
    const int cg = tid % 16;
    const int rg = tid / 16;

    float acc[8][8] = {};

    for (int kc = 0; kc < K; kc += KC) {
        __syncthreads();
        for (int i = tid; i < KC * (TN / 4); i += 256) {
            int k = i / (TN / 4), c4 = i % (TN / 4);
            ((float4*)sW[k])[c4] = *(const float4*)&W[(size_t)(kc + k) * TN + c4 * 4];
        }
        for (int i = tid; i < (KC / 4) * 128; i += 256) {
            int r = i & 127, k4 = i >> 7;
            float4 v = {0.f, 0.f, 0.f, 0.f};
            if (r < rows) v = *(const float4*)&X[(size_t)(row0 + r) * K + kc + k4 * 4];
            sXT[k4 * 4 + 0][r] = v.x;
            sXT[k4 * 4 + 1][r] = v.y;
            sXT[k4 * 4 + 2][r] = v.z;
            sXT[k4 * 4 + 3][r] = v.w;
        }
        __syncthreads();
#pragma unroll 4
        for (int k = 0; k < KC; ++k) {
            float wv[8], xv[8];
            *(float4*)&wv[0] = *(const float4*)&sW[k][cg * 4];
            *(float4*)&wv[4] = *(const float4*)&sW[k][cg * 4 + 64];
            *(float4*)&xv[0] = *(const float4*)&sXT[k][rg * 4];
            *(float4*)&xv[4] = *(const float4*)&sXT[k][rg * 4 + 64];
#pragma unroll
            for (int i = 0; i < 8; ++i)
#pragma unroll
                for (int j = 0; j < 8; ++j)
                    acc[i][j] += xv[i] * wv[j];
        }
    }
#pragma unroll
    for (int i = 0; i < 8; ++i) {
        const int r = (i < 4) ? rg * 4 + i : 64 + rg * 4 + (i - 4);
        if (r < rows) {
#pragma unroll
            for (int half = 0; half < 2; ++half) {
                const int c = cg * 4 + half * 64;
                if (OUTHILO) {
                    ushort4 h4, l4;
                    ushort* hp = (ushort*)&h4; ushort* lp = (ushort*)&l4;
#pragma unroll
                    for (int j = 0; j < 4; ++j) {
                        float v = fmaxf(acc[i][half * 4 + j] + bias[c + j], 0.f);
                        split_bf(v, hp[j], lp[j]);
                    }
                    *(ushort4*)&Chi[(size_t)(row0 + r) * TN + c] = h4;
                    *(ushort4*)&Clo[(size_t)(row0 + r) * TN + c] = l4;
                } else {
                    float4 outv;
                    float* o = (float*)&outv;
#pragma unroll
                    for (int j = 0; j < 4; ++j)
                        o[j] = fmaxf(acc[i][half * 4 + j] + bias[c + j], 0.f);
                    *(float4*)&Cf[(size_t)(row0 + r) * TN + c] = outv;
                }
            }
        }
    }
}

// ============ fused weight transpose + split ============
// msg_w[l]: [256][128] row-major -> WT[l]: [256 cols][128 k]
//   (col<128 -> W_top[k][col], col>=128 -> W_bot[k][col-128])
// lin_w[l]: [128][128] -> LT[l][n][k]
__global__ __launch_bounds__(256)
void tconv_all(const float* __restrict__ MW, const float* __restrict__ LW,
               ushort* __restrict__ WThi, ushort* __restrict__ WTlo,
               ushort* __restrict__ LThi, ushort* __restrict__ LTlo)
{
    int idx = blockIdx.x * 256 + threadIdx.x;
    if (idx < 3 * 32768) {
        int l = idx >> 15, r = idx & 32767;
        int row = r >> 7, c = r & 127;
        int k, col;
        if (row < 128) { k = row; col = c; } else { k = row - 128; col = 128 + c; }
        ushort hi, lo;
        split_bf(MW[idx], hi, lo);
        size_t o = (size_t)l * 32768 + (size_t)col * 128 + k;
        WThi[o] = hi; WTlo[o] = lo;
    } else {
        int j = idx - 3 * 32768;
        if (j >= 3 * 16384) return;
        int l = j >> 14, r = j & 16383;
        int k = r >> 7, nn = r & 127;
        ushort hi, lo;
        split_bf(LW[j], hi, lo);
        size_t o = (size_t)l * 16384 + (size_t)nn * 128 + k;
        LThi[o] = hi; LTlo[o] = lo;
    }
}

// ============ CSR build ============
__global__ __launch_bounds__(256)
void hist_kernel(const int* __restrict__ idx, int* __restrict__ deg, int n)
{
    int i = blockIdx.x * 256 + threadIdx.x;
    if (i < n) atomicAdd(&deg[idx[i]], 1);
}

__global__ __launch_bounds__(256)
void scan_stage1(const int* __restrict__ in, int* __restrict__ excl,
                 int* __restrict__ partial, int n)
{
    const int tid = threadIdx.x;
    const int base = blockIdx.x * 1024 + tid * 4;
    int v[4];
    int s = 0;
#pragma unroll
    for (int i = 0; i < 4; ++i) {
        int t = (base + i < n) ? in[base + i] : 0;
        v[i] = s; s += t;
    }
    __shared__ int warpsum[4];
    const int lane = tid & 63, wid = tid >> 6;
    int pre = s;
#pragma unroll
    for (int off = 1; off < 64; off <<= 1) {
        int t = __shfl_up(pre, off);
        if (lane >= off) pre += t;
    }
    if (lane == 63) warpsum[wid] = pre;
    __syncthreads();
    int wo = 0;
    for (int w = 0; w < wid; ++w) wo += warpsum[w];
    const int thread_excl = wo + pre - s;
#pragma unroll
    for (int i = 0; i < 4; ++i)
        if (base + i < n) excl[base + i] = thread_excl + v[i];
    if (partial && tid == 255) partial[blockIdx.x] = wo + pre;
}

__global__ __launch_bounds__(256)
void scan_stage2(int* __restrict__ partial, int nb)
{
    __shared__ int tmp[256];
    const int tid = threadIdx.x;
    int v = (tid < nb) ? partial[tid] : 0;
    tmp[tid] = v;
    __syncthreads();
    for (int off = 1; off < 256; off <<= 1) {
        int t = (tid >= off) ? tmp[tid - off] : 0;
        __syncthreads();
        tmp[tid] += t;
        __syncthreads();
    }
    if (tid < nb) partial[tid] = tmp[tid] - v;
}

__global__ __launch_bounds__(256)
void scan_stage3(int* __restrict__ excl, const int* __restrict__ partial, int n)
{
    const int base = blockIdx.x * 1024 + threadIdx.x * 4;
    const int p = partial[blockIdx.x];
#pragma unroll
    for (int i = 0; i < 4; ++i)
        if (base + i < n) excl[base + i] += p;
}

__global__ __launch_bounds__(256)
void csr_fill(const int* __restrict__ src, const int* __restrict__ dst,
              const int* __restrict__ rowptr, int* __restrict__ cursor,
              int* __restrict__ csr_src, int E)
{
    int e = blockIdx.x * 256 + threadIdx.x;
    if (e >= E) return;
    int d = dst[e];
    int pos = atomicAdd(&cursor[d], 1);
    csr_src[rowptr[d] + pos] = src[e];
}

// ============ gather: aggr[v] = sum relu(AB[v][0:128] + AB[s][128:256] + mb) -> hi/lo ============
__global__ __launch_bounds__(256)
void gather_msg(const float* __restrict__ AB, const float* __restrict__ mb,
                const int* __restrict__ rowptr, const int* __restrict__ deg,
                const int* __restrict__ csr_src,
                ushort* __restrict__ AGhi, ushort* __restrict__ AGlo, int n)
{
    const int v = blockIdx.x * 8 + (threadIdx.x >> 5);
    if (v >= n) return;
    const int f = (threadIdx.x & 31) * 4;
    float4 a = *(const float4*)&AB[(size_t)v * 256 + f];
    float4 m = *(const float4*)&mb[f];
    const float ax = a.x + m.x, ay = a.y + m.y, az = a.z + m.z, aw = a.w + m.w;
    float4 acc = {0.f, 0.f, 0.f, 0.f};
    const int start = rowptr[v];
    const int cnt = deg[v];
    for (int i = 0; i < cnt; ++i) {
        int s = csr_src[start + i];
        float4 b = *(const float4*)&AB[(size_t)s * 256 + 128 + f];
        acc.x += fmaxf(ax + b.x, 0.f);
        acc.y += fmaxf(ay + b.y, 0.f);
        acc.z += fmaxf(az + b.z, 0.f);
        acc.w += fmaxf(aw + b.w, 0.f);
    }
    ushort4 h4, l4;
    ushort* hp = (ushort*)&h4; ushort* lp = (ushort*)&l4;
    split_bf(acc.x, hp[0], lp[0]);
    split_bf(acc.y, hp[1], lp[1]);
    split_bf(acc.z, hp[2], lp[2]);
    split_bf(acc.w, hp[3], lp[3]);
    *(ushort4*)&AGhi[(size_t)v * HIDDEN + f] = h4;
    *(ushort4*)&AGlo[(size_t)v * HIDDEN + f] = l4;
}

// ============ pooling ============
__global__ __launch_bounds__(128)
void pool_mean(const ushort* __restrict__ Hhi, const ushort* __restrict__ Hlo,
               const int* __restrict__ rp, const int* __restrict__ cnt,
               float* __restrict__ fused, int half)
{
    const int b = blockIdx.x;
    const int f = threadIdx.x;
    const int start = rp[b];
    const int c = cnt[b];
    float acc = 0.f;
    for (int i = 0; i < c; ++i) {
        size_t o = (size_t)(start + i) * HIDDEN + f;
        acc += bf2f(Hhi[o]) + bf2f(Hlo[o]);
    }
    fused[(size_t)b * (2 * HIDDEN) + half * HIDDEN + f] = acc / fmaxf((float)c, 1.0f);
}

// ============ head ============
__global__ __launch_bounds__(128)
void head_kernel(const float* __restrict__ fused,
                 const float* __restrict__ muw, const float* __restrict__ mub,
                 const float* __restrict__ lvw, const float* __restrict__ lvb,
                 float* __restrict__ mu, float* __restrict__ lv)
{
    __shared__ float sf[2 * HIDDEN];
    const int b = blockIdx.x;
    const int t = threadIdx.x;
    sf[t] = fused[(size_t)b * 256 + t];
    sf[t + 128] = fused[(size_t)b * 256 + t + 128];
    __syncthreads();
    if (t < ZDIM) {
        float accm = mub[t], accl = lvb[t];
        for (int k = 0; k < 2 * HIDDEN; ++k) {
            float fv = sf[k];
            accm += fv * muw[(size_t)k * ZDIM + t];
            accl += fv * lvw[(size_t)k * ZDIM + t];
        }
        mu[(size_t)b * ZDIM + t] = accm;
        lv[(size_t)b * ZDIM + t] = accl;
    }
}

extern "C" void kernel_launch(void* const* d_in, const int* in_sizes, int n_in,
                              void* d_out, int out_size, void* d_ws, size_t ws_size,
                              hipStream_t stream)
{
    const float* tree_x   = (const float*)d_in[0];
    const int*   tree_ei  = (const int*)d_in[1];
    const float* graph_x  = (const float*)d_in[2];
    const int*   graph_ei = (const int*)d_in[3];
    const int*   batch_t  = (const int*)d_in[4];
    const int*   batch_g  = (const int*)d_in[5];
    const float* t_proj_w = (const float*)d_in[6];
    const float* t_proj_b = (const float*)d_in[7];
    const float* t_msg_w  = (const float*)d_in[8];
    const float* t_msg_b  = (const float*)d_in[9];
    const float* t_lin_w  = (const float*)d_in[10];
    const float* t_lin_b  = (const float*)d_in[11];
    const float* g_proj_w = (const float*)d_in[12];
    const float* g_proj_b = (const float*)d_in[13];
    const float* g_msg_w  = (const float*)d_in[14];
    const float* g_msg_b  = (const float*)d_in[15];
    const float* g_lin_w  = (const float*)d_in[16];
    const float* g_lin_b  = (const float*)d_in[17];
    const float* mu_w     = (const float*)d_in[18];
    const float* mu_b     = (const float*)d_in[19];
    const float* lv_w     = (const float*)d_in[20];
    const float* lv_b     = (const float*)d_in[21];

    const int n_tree  = in_sizes[0] / 64;
    const int e_tree  = in_sizes[1] / 2;
    const int n_graph = in_sizes[2] / 32;
    const int e_graph = in_sizes[3] / 2;

    float* out    = (float*)d_out;
    float* mu_out = out;
    float* lv_out = out + (size_t)NGRAPHS * ZDIM;
    float* fused  = out + (size_t)2 * NGRAPHS * ZDIM;

    // ---- workspace carve (byte-based) ----
    char* base = (char*)d_ws;
    const size_t nmax = (size_t)n_graph;
    float*  AB   = (float*)base;  base += nmax * 256 * sizeof(float);
    ushort* Hhi  = (ushort*)base; base += nmax * 128 * sizeof(ushort);
    ushort* Hlo  = (ushort*)base; base += nmax * 128 * sizeof(ushort);
    ushort* WThi = (ushort*)base; base += (size_t)3 * 32768 * sizeof(ushort);
    ushort* WTlo = (ushort*)base; base += (size_t)3 * 32768 * sizeof(ushort);
    ushort* LThi = (ushort*)base; base += (size_t)3 * 16384 * sizeof(ushort);
    ushort* LTlo = (ushort*)base; base += (size_t)3 * 16384 * sizeof(ushort);
    int* deg     = (int*)base;    base += nmax * sizeof(int);   // deg, cursor, degb contiguous
    int* cursor  = (int*)base;    base += nmax * sizeof(int);   //   (stride nmax!) -> single memset
    int* degb    = (int*)base;    base += NGRAPHS * sizeof(int);
    int* rowptr  = (int*)base;    base += nmax * sizeof(int);
    int* csr_src = (int*)base;    base += (size_t)e_graph * sizeof(int);
    int* partial = (int*)base;    base += 256 * sizeof(int);
    int* rpb     = (int*)base;

    auto run_encoder = [&](const float* x, int Kin, int n, int E, const int* ei,
                           const int* batch,
                           const float* proj_w, const float* proj_b,
                           const float* msg_w, const float* msg_b,
                           const float* lin_w, const float* lin_b, int half) {
        const int nb = (n + 1023) / 1024;
        const int gb128 = (n + 127) / 128;
        const int* src = ei;        // edge_index[0]  (x_j)
        const int* dst = ei + E;    // edge_index[1]  (x_i / aggregation target)

        // ---- CSR build ----
        // NOTE: deg/cursor are carved with stride nmax (= n_graph), NOT n.
        // Memset must cover the full carve: deg[nmax] + cursor[nmax] + degb[NGRAPHS].
        hipMemsetAsync(deg, 0, (2 * nmax + NGRAPHS) * sizeof(int), stream);
        hist_kernel<<<(E + 255) / 256, 256, 0, stream>>>(dst, deg, E);
        scan_stage1<<<nb, 256, 0, stream>>>(deg, rowptr, partial, n);
        scan_stage2<<<1, 256, 0, stream>>>(partial, nb);
        scan_stage3<<<nb, 256, 0, stream>>>(rowptr, partial, n);
        csr_fill<<<(E + 255) / 256, 256, 0, stream>>>(src, dst, rowptr, cursor, csr_src, E);

        // ---- batch ranges (batch sorted) ----
        hist_kernel<<<(n + 255) / 256, 256, 0, stream>>>(batch, degb, n);
        scan_stage1<<<1, 256, 0, stream>>>(degb, rpb, nullptr, NGRAPHS);

        // ---- weight transpose + split (fused) ----
        tconv_all<<<(3 * 32768 + 3 * 16384 + 255) / 256, 256, 0, stream>>>(
            msg_w, lin_w, WThi, WTlo, LThi, LTlo);

        // ---- input projection -> h hi/lo ----
        if (Kin == 64)
            gemm_rt<64, true><<<gb128, 256, 0, stream>>>(
                x, proj_w, proj_b, nullptr, Hhi, Hlo, n);
        else
            gemm_rt<32, true><<<gb128, 256, 0, stream>>>(
                x, proj_w, proj_b, nullptr, Hhi, Hlo, n);

        for (int l = 0; l < NLAYERS; ++l) {
            // AB = h @ [W_top | W_bot]  -> f32 [n, 256]
            gemm_mfma<256, false, false, false><<<gb128, 512, 0, stream>>>(
                Hhi, Hlo, WThi + (size_t)l * 32768, WTlo + (size_t)l * 32768,
                nullptr, AB, nullptr, nullptr, n);
            // aggr -> hi/lo (overwrites h planes; h is dead)
            gather_msg<<<(n + 7) / 8, 256, 0, stream>>>(
                AB, msg_b + (size_t)l * HIDDEN, rowptr, deg, csr_src, Hhi, Hlo, n);
            // h' = relu(aggr @ lin + b) -> hi/lo in place
            gemm_mfma<128, true, true, true><<<gb128, 512, 0, stream>>>(
                Hhi, Hlo, LThi + (size_t)l * 16384, LTlo + (size_t)l * 16384,
                lin_b + (size_t)l * HIDDEN, nullptr, Hhi, Hlo, n);
        }
        pool_mean<<<NGRAPHS, 128, 0, stream>>>(Hhi, Hlo, rpb, degb, fused, half);
    };

    run_encoder(tree_x, 64, n_tree, e_tree, tree_ei, batch_t,
                t_proj_w, t_proj_b, t_msg_w, t_msg_b, t_lin_w, t_lin_b, 0);
    run_encoder(graph_x, 32, n_graph, e_graph, graph_ei, batch_g,
                g_proj_w, g_proj_b, g_msg_w, g_msg_b, g_lin_w, g_lin_b, 1);

    head_kernel<<<NGRAPHS, 128, 0, stream>>>(fused, mu_w, mu_b, lv_w, lv_b, mu_out, lv_out);
}

// Round 11
// 679.322 us; speedup vs baseline: 1.5409x; 1.5409x over previous
//
#include <hip/hip_runtime.h>

#define HIDDEN 128
#define ZDIM 56
#define NLAYERS 3
#define NGRAPHS 1024

typedef __attribute__((ext_vector_type(8))) short short8v;
typedef __attribute__((ext_vector_type(4))) float float4v;

__device__ __forceinline__ ushort f2bf(float v) {
    union { float f; unsigned u; } x; x.f = v;
    unsigned r = x.u + 0x7fffu + ((x.u >> 16) & 1u);   // RNE
    return (ushort)(r >> 16);
}
__device__ __forceinline__ float bf2f(ushort h) {
    union { unsigned u; float f; } x; x.u = ((unsigned)h) << 16;
    return x.f;
}
__device__ __forceinline__ void split_bf(float v, ushort& hi, ushort& lo) {
    hi = f2bf(v);
    lo = f2bf(v - bf2f(hi));
}
__device__ __forceinline__ void gload_lds16(const void* g, void* l) {
    __builtin_amdgcn_global_load_lds(
        (const __attribute__((address_space(1))) unsigned int*)g,
        (__attribute__((address_space(3))) unsigned int*)l, 16, 0, 0);
}

// ================= unified row-space layout =================
// buf = f32 [NTOT][256] (1024 B/row). Per row v:
//   left  half bytes [0,512):   f32 A (gemm256 out) -> then aggr hi/lo (gather out)
//   right half bytes [512,1024): f32 B (gemm256 out) / h hi/lo (proj & lin out)
// ushort view U: row stride 512; left hi @0, left lo @128; right hi @256, right lo @384.
// Tree rows [0, ntp); graph rows [ntp, NTOT). Pad rows: finite garbage, gather zeroes
// them (deg=0), never pooled.

// ============ split-bf16 MFMA GEMM (R7 structure, fused encoders, strided X) ============
// 3 MFMAs per (hi,lo) pair: ah*bh + ah*bl + al*bh  — identical order to verified R7.
template<int TN, bool RELU, bool BIAS, bool OUTHILO>
__global__ __launch_bounds__(512, 4)
void gemm_mfma(const ushort* __restrict__ Xhi, const ushort* __restrict__ Xlo, int XS,
               const ushort* __restrict__ WThi_t, const ushort* __restrict__ WTlo_t,
               const ushort* __restrict__ WThi_g, const ushort* __restrict__ WTlo_g,
               const float* __restrict__ bias_t, const float* __restrict__ bias_g,
               float* __restrict__ Cf,
               ushort* __restrict__ Chi, ushort* __restrict__ Clo, int CS,
               int ntp)
{
    constexpr int CPW = TN / 64;            // col frags per wave
    constexpr int XCELLS = 2 * 4 * 128;     // 1024 16B-cells
    constexpr int WCELLS = 2 * 4 * TN;
    __shared__ ushort smem[(XCELLS + WCELLS) * 8];
    ushort* sX = smem;
    ushort* sW = smem + XCELLS * 8;

    const int tid = threadIdx.x;
    const int w = tid >> 6, l = tid & 63;
    const int wr = w >> 2;                  // row half
    const int wc = w & 3;                   // col group
    const int seg = l >> 4, lr = l & 15;
    const int row0 = blockIdx.x * 128;
    const bool g = (row0 >= ntp);
    const ushort* __restrict__ WThi = g ? WThi_g : WThi_t;
    const ushort* __restrict__ WTlo = g ? WTlo_g : WTlo_t;
    const float*  __restrict__ bias = g ? bias_g : bias_t;

    float4v acc[4][CPW];
#pragma unroll
    for (int i = 0; i < 4; ++i)
#pragma unroll
        for (int j = 0; j < CPW; ++j) {
            float4v z = {0.f, 0.f, 0.f, 0.f};
            acc[i][j] = z;
        }

    for (int kc = 0; kc < 128; kc += 32) {
        __syncthreads();
        // ---- stage X (1024 cells, linear; all padded rows valid) ----
#pragma unroll
        for (int t = 0; t < XCELLS / 512; ++t) {
            const int cbase = (w * (XCELLS / 512) + t) * 64;
            const int c = cbase + l;
            const int plane = c >> 9, rem = c & 511, sg = rem >> 7, r = rem & 127;
            const ushort* srcp = plane ? Xlo : Xhi;
            gload_lds16(&srcp[(size_t)(row0 + r) * XS + kc + sg * 8],
                        (char*)sX + (size_t)cbase * 16);
        }
        // ---- stage W ----
#pragma unroll
        for (int t = 0; t < WCELLS / 512; ++t) {
            const int cbase = (w * (WCELLS / 512) + t) * 64;
            const int c = cbase + l;
            const int plane = (c >= WCELLS / 2) ? 1 : 0;
            const int rem = c - plane * (WCELLS / 2);
            const int sg = rem / TN, col = rem % TN;
            const ushort* srcp = plane ? WTlo : WThi;
            gload_lds16(&srcp[(size_t)col * 128 + kc + sg * 8],
                        (char*)sW + (size_t)cbase * 16);
        }
        __syncthreads();

        short8v ah[4], al[4];
#pragma unroll
        for (int i = 0; i < 4; ++i) {
            const int off = (seg * 128 + wr * 64 + i * 16 + lr) * 8;
            ah[i] = *(const short8v*)&sX[off];
            al[i] = *(const short8v*)&sX[(XCELLS / 2) * 8 + off];
        }
#pragma unroll
        for (int j = 0; j < CPW; ++j) {
            const int col = (wc * CPW + j) * 16 + lr;
            const int off = (seg * TN + col) * 8;
            short8v bh = *(const short8v*)&sW[off];
            short8v bl = *(const short8v*)&sW[(WCELLS / 2) * 8 + off];
#pragma unroll
            for (int i = 0; i < 4; ++i) {
                acc[i][j] = __builtin_amdgcn_mfma_f32_16x16x32_bf16(ah[i], bh, acc[i][j], 0, 0, 0);
                acc[i][j] = __builtin_amdgcn_mfma_f32_16x16x32_bf16(ah[i], bl, acc[i][j], 0, 0, 0);
                acc[i][j] = __builtin_amdgcn_mfma_f32_16x16x32_bf16(al[i], bh, acc[i][j], 0, 0, 0);
            }
        }
    }

    // epilogue (R7 direct stores; padded rows always writable)
#pragma unroll
    for (int i = 0; i < 4; ++i) {
#pragma unroll
        for (int j = 0; j < CPW; ++j) {
            const int gcol = (wc * CPW + j) * 16 + lr;
            const float bv = BIAS ? bias[gcol] : 0.f;
#pragma unroll
            for (int r = 0; r < 4; ++r) {
                const int grow = row0 + wr * 64 + i * 16 + seg * 4 + r;
                float v = acc[i][j][r] + bv;
                if (RELU) v = fmaxf(v, 0.f);
                if (OUTHILO) {
                    ushort hi, lo;
                    split_bf(v, hi, lo);
                    Chi[(size_t)grow * CS + gcol] = hi;
                    Clo[(size_t)grow * CS + gcol] = lo;
                } else {
                    Cf[(size_t)grow * TN + gcol] = v;
                }
            }
        }
    }
}

// ============ f32 vector GEMM for input projection (K=32/64) -> hi/lo @ stride CS ============
template<int K>
__global__ __launch_bounds__(256)
void gemm_rt(const float* __restrict__ X, const float* __restrict__ W,
             const float* __restrict__ bias,
             ushort* __restrict__ Chi, ushort* __restrict__ Clo, int CS, int n)
{
    constexpr int TN = 128;
    constexpr int KC = 32;
    __shared__ float sXT[KC][128];
    __shared__ float sW[KC][TN];

    const int tid  = threadIdx.x;
    const int row0 = blockIdx.x * 128;
    const int rows = min(128, n - row0);
    if (rows <= 0) return;
    const int cg = tid % 16;
    const int rg = tid / 16;

    float acc[8][8] = {};

    for (int kc = 0; kc < K; kc += KC) {
        __syncthreads();
        for (int i = tid; i < KC * (TN / 4); i += 256) {
            int k = i / (TN / 4), c4 = i % (TN / 4);
            ((float4*)sW[k])[c4] = *(const float4*)&W[(size_t)(kc + k) * TN + c4 * 4];
        }
        for (int i = tid; i < (KC / 4) * 128; i += 256) {
            int r = i & 127, k4 = i >> 7;
            float4 v = {0.f, 0.f, 0.f, 0.f};
            if (r < rows) v = *(const float4*)&X[(size_t)(row0 + r) * K + kc + k4 * 4];
            sXT[k4 * 4 + 0][r] = v.x;
            sXT[k4 * 4 + 1][r] = v.y;
            sXT[k4 * 4 + 2][r] = v.z;
            sXT[k4 * 4 + 3][r] = v.w;
        }
        __syncthreads();
#pragma unroll 4
        for (int k = 0; k < KC; ++k) {
            float wv[8], xv[8];
            *(float4*)&wv[0] = *(const float4*)&sW[k][cg * 4];
            *(float4*)&wv[4] = *(const float4*)&sW[k][cg * 4 + 64];
            *(float4*)&xv[0] = *(const float4*)&sXT[k][rg * 4];
            *(float4*)&xv[4] = *(const float4*)&sXT[k][rg * 4 + 64];
#pragma unroll
            for (int i = 0; i < 8; ++i)
#pragma unroll
                for (int j = 0; j < 8; ++j)
                    acc[i][j] += xv[i] * wv[j];
        }
    }
#pragma unroll
    for (int i = 0; i < 8; ++i) {
        const int r = (i < 4) ? rg * 4 + i : 64 + rg * 4 + (i - 4);
        if (r < rows) {
#pragma unroll
            for (int half = 0; half < 2; ++half) {
                const int c = cg * 4 + half * 64;
                ushort4 h4, l4;
                ushort* hp = (ushort*)&h4; ushort* lp = (ushort*)&l4;
#pragma unroll
                for (int j = 0; j < 4; ++j) {
                    float v = fmaxf(acc[i][half * 4 + j] + bias[c + j], 0.f);
                    split_bf(v, hp[j], lp[j]);
                }
                *(ushort4*)&Chi[(size_t)(row0 + r) * CS + c] = h4;
                *(ushort4*)&Clo[(size_t)(row0 + r) * CS + c] = l4;
            }
        }
    }
}

// ============ weight transpose + split, both encoders ============
__global__ __launch_bounds__(256)
void tconv_all(const float* __restrict__ MWt, const float* __restrict__ MWg,
               const float* __restrict__ LWt, const float* __restrict__ LWg,
               ushort* __restrict__ WThi, ushort* __restrict__ WTlo,
               ushort* __restrict__ LThi, ushort* __restrict__ LTlo)
{
    int idx = blockIdx.x * 256 + threadIdx.x;
    if (idx < 2 * 98304) {                       // msg weights
        int enc = idx / 98304, r2 = idx % 98304;
        int l = r2 >> 15, r = r2 & 32767;
        int row = r >> 7, c = r & 127;
        int k, col;
        if (row < 128) { k = row; col = c; } else { k = row - 128; col = 128 + c; }
        const float* src = enc ? MWg : MWt;
        ushort hi, lo;
        split_bf(src[r2], hi, lo);
        size_t o = (size_t)(enc * 3 + l) * 32768 + (size_t)col * 128 + k;
        WThi[o] = hi; WTlo[o] = lo;
    } else {                                     // lin weights
        int j = idx - 2 * 98304;
        if (j >= 2 * 49152) return;
        int enc = j / 49152, r2 = j % 49152;
        int l = r2 >> 14, r = r2 & 16383;
        int k = r >> 7, nn = r & 127;
        const float* src = enc ? LWg : LWt;
        ushort hi, lo;
        split_bf(src[r2], hi, lo);
        size_t o = (size_t)(enc * 3 + l) * 16384 + (size_t)nn * 128 + k;
        LThi[o] = hi; LTlo[o] = lo;
    }
}

// ============ CSR build (unified node space) ============
__global__ __launch_bounds__(256)
void hist_all(const int* __restrict__ tei, const int* __restrict__ gei,
              int et, int eg, int ntp, int* __restrict__ deg)
{
    int i = blockIdx.x * 256 + threadIdx.x;
    if (i < et) atomicAdd(&deg[tei[et + i]], 1);
    else if (i < et + eg) atomicAdd(&deg[gei[eg + (i - et)] + ntp], 1);
}

__global__ __launch_bounds__(256)
void scan_stage1(const int* __restrict__ in, int* __restrict__ excl,
                 int* __restrict__ partial, int n)
{
    const int tid = threadIdx.x;
    const int base = blockIdx.x * 1024 + tid * 4;
    int v[4];
    int s = 0;
#pragma unroll
    for (int i = 0; i < 4; ++i) {
        int t = (base + i < n) ? in[base + i] : 0;
        v[i] = s; s += t;
    }
    __shared__ int warpsum[4];
    const int lane = tid & 63, wid = tid >> 6;
    int pre = s;
#pragma unroll
    for (int off = 1; off < 64; off <<= 1) {
        int t = __shfl_up(pre, off);
        if (lane >= off) pre += t;
    }
    if (lane == 63) warpsum[wid] = pre;
    __syncthreads();
    int wo = 0;
    for (int w = 0; w < wid; ++w) wo += warpsum[w];
    const int thread_excl = wo + pre - s;
#pragma unroll
    for (int i = 0; i < 4; ++i)
        if (base + i < n) excl[base + i] = thread_excl + v[i];
    if (partial && tid == 255) partial[blockIdx.x] = wo + pre;
}

__global__ __launch_bounds__(256)
void scan_stage2(int* __restrict__ partial, int nb)
{
    __shared__ int tmp[256];
    const int tid = threadIdx.x;
    int v = (tid < nb) ? partial[tid] : 0;
    tmp[tid] = v;
    __syncthreads();
    for (int off = 1; off < 256; off <<= 1) {
        int t = (tid >= off) ? tmp[tid - off] : 0;
        __syncthreads();
        tmp[tid] += t;
        __syncthreads();
    }
    if (tid < nb) partial[tid] = tmp[tid] - v;
}

__global__ __launch_bounds__(256)
void scan_stage3(int* __restrict__ excl, const int* __restrict__ partial, int n)
{
    const int base = blockIdx.x * 1024 + threadIdx.x * 4;
    const int p = partial[blockIdx.x];
#pragma unroll
    for (int i = 0; i < 4; ++i)
        if (base + i < n) excl[base + i] += p;
}

__global__ __launch_bounds__(256)
void csr_fill_all(const int* __restrict__ tei, const int* __restrict__ gei,
                  int et, int eg, int ntp,
                  const int* __restrict__ rowptr, int* __restrict__ cursor,
                  int* __restrict__ csr_src)
{
    int e = blockIdx.x * 256 + threadIdx.x;
    int s, d;
    if (e < et) { s = tei[e]; d = tei[et + e]; }
    else if (e < et + eg) { int i = e - et; s = gei[i] + ntp; d = gei[eg + i] + ntp; }
    else return;
    int pos = atomicAdd(&cursor[d], 1);
    csr_src[rowptr[d] + pos] = s;
}

// ============ batch ranges via binary search (batch sorted) ============
__global__ __launch_bounds__(256)
void rpb_search(const int* __restrict__ batch_t, int nt,
                const int* __restrict__ batch_g, int ng, int* __restrict__ rpb)
{
    int t = blockIdx.x * 256 + threadIdx.x;
    if (t >= 2 * (NGRAPHS + 1)) return;
    const int enc = t / (NGRAPHS + 1);
    const int b = t % (NGRAPHS + 1);
    const int* batch = enc ? batch_g : batch_t;
    const int n = enc ? ng : nt;
    int lo = 0, hi = n;
    while (lo < hi) { int mid = (lo + hi) >> 1; if (batch[mid] < b) lo = mid + 1; else hi = mid; }
    rpb[t] = lo;
}

// ============ gather: aggr[v] = sum relu(A[v] + B[s] + mb) -> left-half hi/lo ============
__global__ __launch_bounds__(256)
void gather_msg(float* __restrict__ buf, const float* __restrict__ mbt,
                const float* __restrict__ mbg,
                const int* __restrict__ rowptr, const int* __restrict__ deg,
                const int* __restrict__ csr_src, int ntp, int ntot)
{
    const int v = blockIdx.x * 8 + (threadIdx.x >> 5);
    if (v >= ntot) return;
    const int f = (threadIdx.x & 31) * 4;
    const float* mb = (v < ntp) ? mbt : mbg;
    float4 a = *(const float4*)&buf[(size_t)v * 256 + f];
    float4 m = *(const float4*)&mb[f];
    const float ax = a.x + m.x, ay = a.y + m.y, az = a.z + m.z, aw = a.w + m.w;
    float4 acc = {0.f, 0.f, 0.f, 0.f};
    const int start = rowptr[v];
    const int cnt = deg[v];
    for (int i = 0; i < cnt; ++i) {
        int s = csr_src[start + i];
        float4 b = *(const float4*)&buf[(size_t)s * 256 + 128 + f];
        acc.x += fmaxf(ax + b.x, 0.f);
        acc.y += fmaxf(ay + b.y, 0.f);
        acc.z += fmaxf(az + b.z, 0.f);
        acc.w += fmaxf(aw + b.w, 0.f);
    }
    ushort4 h4, l4;
    ushort* hp = (ushort*)&h4; ushort* lp = (ushort*)&l4;
    split_bf(acc.x, hp[0], lp[0]);
    split_bf(acc.y, hp[1], lp[1]);
    split_bf(acc.z, hp[2], lp[2]);
    split_bf(acc.w, hp[3], lp[3]);
    ushort* U = (ushort*)buf;
    *(ushort4*)&U[(size_t)v * 512 + f] = h4;           // left hi
    *(ushort4*)&U[(size_t)v * 512 + 128 + f] = l4;     // left lo
}

// ============ pooling (right-half h, per-graph contiguous ranges) ============
__global__ __launch_bounds__(128)
void pool_mean(const ushort* __restrict__ U, const int* __restrict__ rpb,
               int ntp, float* __restrict__ fused)
{
    const int bid = blockIdx.x;
    const int enc = bid >> 10, b = bid & 1023;
    const int f = threadIdx.x;
    const int base_i = enc * (NGRAPHS + 1) + b;
    const int start = rpb[base_i];
    const int c = rpb[base_i + 1] - start;
    const int row0 = start + (enc ? ntp : 0);
    float acc = 0.f;
    for (int i = 0; i < c; ++i) {
        size_t o = (size_t)(row0 + i) * 512 + 256 + f;
        acc += bf2f(U[o]) + bf2f(U[o + 128]);
    }
    fused[(size_t)b * 256 + enc * 128 + f] = acc / fmaxf((float)c, 1.0f);
}

// ============ head ============
__global__ __launch_bounds__(128)
void head_kernel(const float* __restrict__ fused,
                 const float* __restrict__ muw, const float* __restrict__ mub,
                 const float* __restrict__ lvw, const float* __restrict__ lvb,
                 float* __restrict__ mu, float* __restrict__ lv)
{
    __shared__ float sf[2 * HIDDEN];
    const int b = blockIdx.x;
    const int t = threadIdx.x;
    sf[t] = fused[(size_t)b * 256 + t];
    sf[t + 128] = fused[(size_t)b * 256 + t + 128];
    __syncthreads();
    if (t < ZDIM) {
        float accm = mub[t], accl = lvb[t];
        for (int k = 0; k < 2 * HIDDEN; ++k) {
            float fv = sf[k];
            accm += fv * muw[(size_t)k * ZDIM + t];
            accl += fv * lvw[(size_t)k * ZDIM + t];
        }
        mu[(size_t)b * ZDIM + t] = accm;
        lv[(size_t)b * ZDIM + t] = accl;
    }
}

extern "C" void kernel_launch(void* const* d_in, const int* in_sizes, int n_in,
                              void* d_out, int out_size, void* d_ws, size_t ws_size,
                              hipStream_t stream)
{
    const float* tree_x   = (const float*)d_in[0];
    const int*   tree_ei  = (const int*)d_in[1];
    const float* graph_x  = (const float*)d_in[2];
    const int*   graph_ei = (const int*)d_in[3];
    const int*   batch_t  = (const int*)d_in[4];
    const int*   batch_g  = (const int*)d_in[5];
    const float* t_proj_w = (const float*)d_in[6];
    const float* t_proj_b = (const float*)d_in[7];
    const float* t_msg_w  = (const float*)d_in[8];
    const float* t_msg_b  = (const float*)d_in[9];
    const float* t_lin_w  = (const float*)d_in[10];
    const float* t_lin_b  = (const float*)d_in[11];
    const float* g_proj_w = (const float*)d_in[12];
    const float* g_proj_b = (const float*)d_in[13];
    const float* g_msg_w  = (const float*)d_in[14];
    const float* g_msg_b  = (const float*)d_in[15];
    const float* g_lin_w  = (const float*)d_in[16];
    const float* g_lin_b  = (const float*)d_in[17];
    const float* mu_w     = (const float*)d_in[18];
    const float* mu_b     = (const float*)d_in[19];
    const float* lv_w     = (const float*)d_in[20];
    const float* lv_b     = (const float*)d_in[21];

    const int n_tree  = in_sizes[0] / 64;
    const int e_tree  = in_sizes[1] / 2;
    const int n_graph = in_sizes[2] / 32;
    const int e_graph = in_sizes[3] / 2;
    const int E_tot   = e_tree + e_graph;

    const int ntp  = ((n_tree + 127) / 128) * 128;    // padded tree rows
    const int npg  = ((n_graph + 127) / 128) * 128;
    const int NTOT = ntp + npg;
    const int GB   = NTOT / 128;                      // fused GEMM grid

    float* out    = (float*)d_out;
    float* mu_out = out;
    float* lv_out = out + (size_t)NGRAPHS * ZDIM;
    float* fused  = out + (size_t)2 * NGRAPHS * ZDIM;

    // ---- workspace carve ----
    char* base = (char*)d_ws;
    float*  buf  = (float*)base;  base += (size_t)NTOT * 256 * sizeof(float);
    ushort* U    = (ushort*)buf;
    ushort* WThi = (ushort*)base; base += (size_t)6 * 32768 * sizeof(ushort);
    ushort* WTlo = (ushort*)base; base += (size_t)6 * 32768 * sizeof(ushort);
    ushort* LThi = (ushort*)base; base += (size_t)6 * 16384 * sizeof(ushort);
    ushort* LTlo = (ushort*)base; base += (size_t)6 * 16384 * sizeof(ushort);
    int* deg     = (int*)base;    base += (size_t)NTOT * sizeof(int);   // deg+cursor contiguous
    int* cursor  = (int*)base;    base += (size_t)NTOT * sizeof(int);
    int* rowptr  = (int*)base;    base += (size_t)NTOT * sizeof(int);
    int* csr_src = (int*)base;    base += (size_t)E_tot * sizeof(int);
    int* partial = (int*)base;    base += 256 * sizeof(int);
    int* rpb     = (int*)base;    // 2*(NGRAPHS+1)

    const int nb = (NTOT + 1023) / 1024;

    // ---- CSR build (unified) ----
    hipMemsetAsync(deg, 0, (size_t)2 * NTOT * sizeof(int), stream);
    hist_all<<<(E_tot + 255) / 256, 256, 0, stream>>>(tree_ei, graph_ei, e_tree, e_graph, ntp, deg);
    scan_stage1<<<nb, 256, 0, stream>>>(deg, rowptr, partial, NTOT);
    scan_stage2<<<1, 256, 0, stream>>>(partial, nb);
    scan_stage3<<<nb, 256, 0, stream>>>(rowptr, partial, NTOT);
    csr_fill_all<<<(E_tot + 255) / 256, 256, 0, stream>>>(tree_ei, graph_ei, e_tree, e_graph,
                                                          ntp, rowptr, cursor, csr_src);
    rpb_search<<<(2 * (NGRAPHS + 1) + 255) / 256, 256, 0, stream>>>(batch_t, n_tree,
                                                                    batch_g, n_graph, rpb);
    tconv_all<<<(2 * 98304 + 2 * 49152 + 255) / 256, 256, 0, stream>>>(
        t_msg_w, g_msg_w, t_lin_w, g_lin_w, WThi, WTlo, LThi, LTlo);

    // ---- input projections -> right-half h hi/lo ----
    gemm_rt<64><<<(n_tree + 127) / 128, 256, 0, stream>>>(
        tree_x, t_proj_w, t_proj_b, U + 256, U + 384, 512, n_tree);
    gemm_rt<32><<<(n_graph + 127) / 128, 256, 0, stream>>>(
        graph_x, g_proj_w, g_proj_b,
        U + 256 + (size_t)ntp * 512, U + 384 + (size_t)ntp * 512, 512, n_graph);

    // ---- fused layer loop ----
    for (int l = 0; l < NLAYERS; ++l) {
        // AB = h @ [W_top|W_bot] : right-half X -> full-row f32 (in place per block)
        gemm_mfma<256, false, false, false><<<GB, 512, 0, stream>>>(
            U + 256, U + 384, 512,
            WThi + (size_t)l * 32768, WTlo + (size_t)l * 32768,
            WThi + (size_t)(3 + l) * 32768, WTlo + (size_t)(3 + l) * 32768,
            nullptr, nullptr, buf, nullptr, nullptr, 0, ntp);
        // aggr -> left-half hi/lo
        gather_msg<<<NTOT / 8, 256, 0, stream>>>(
            buf, t_msg_b + (size_t)l * HIDDEN, g_msg_b + (size_t)l * HIDDEN,
            rowptr, deg, csr_src, ntp, NTOT);
        // h' = relu(aggr @ lin + b) : left-half X -> right-half hi/lo
        gemm_mfma<128, true, true, true><<<GB, 512, 0, stream>>>(
            U, U + 128, 512,
            LThi + (size_t)l * 16384, LTlo + (size_t)l * 16384,
            LThi + (size_t)(3 + l) * 16384, LTlo + (size_t)(3 + l) * 16384,
            t_lin_b + (size_t)l * HIDDEN, g_lin_b + (size_t)l * HIDDEN,
            nullptr, U + 256, U + 384, 512, ntp);
    }

    pool_mean<<<2 * NGRAPHS, 128, 0, stream>>>(U, rpb, ntp, fused);
    head_kernel<<<NGRAPHS, 128, 0, stream>>>(fused, mu_w, mu_b, lv_w, lv_b, mu_out, lv_out);
}

// Round 12
// 663.707 us; speedup vs baseline: 1.5772x; 1.0235x over previous
//
#include <hip/hip_runtime.h>

#define HIDDEN 128
#define ZDIM 56
#define NLAYERS 3
#define NGRAPHS 1024

typedef __attribute__((ext_vector_type(8))) short short8v;
typedef __attribute__((ext_vector_type(4))) float float4v;

__device__ __forceinline__ ushort f2bf(float v) {
    union { float f; unsigned u; } x; x.f = v;
    unsigned r = x.u + 0x7fffu + ((x.u >> 16) & 1u);   // RNE
    return (ushort)(r >> 16);
}
__device__ __forceinline__ float bf2f(ushort h) {
    union { unsigned u; float f; } x; x.u = ((unsigned)h) << 16;
    return x.f;
}
__device__ __forceinline__ void split_bf(float v, ushort& hi, ushort& lo) {
    hi = f2bf(v);
    lo = f2bf(v - bf2f(hi));
}
__device__ __forceinline__ void gload_lds16(const void* g, void* l) {
    __builtin_amdgcn_global_load_lds(
        (const __attribute__((address_space(1))) unsigned int*)g,
        (__attribute__((address_space(3))) unsigned int*)l, 16, 0, 0);
}

// ================= unified row-space layout =================
// buf = f32 [NTOT][256] (1024 B/row). Per row v:
//   left  half bytes [0,512):   h hi/lo (proj & fused-lin out) -> A part of AB (msg out)
//   right half bytes [512,1024): B part of AB (msg out); read cross-block by gather
// ushort view U: row stride 512; left hi @0, left lo @128.
// Tree rows [0, ntp); graph rows [ntp, NTOT). Pad rows: finite garbage, deg=0.

// ============ split-bf16 MFMA msg GEMM (R11 structure): AB = h @ [Wtop|Wbot] ============
template<int TN>
__global__ __launch_bounds__(512, 4)
void gemm_mfma(const ushort* __restrict__ Xhi, const ushort* __restrict__ Xlo, int XS,
               const ushort* __restrict__ WThi_t, const ushort* __restrict__ WTlo_t,
               const ushort* __restrict__ WThi_g, const ushort* __restrict__ WTlo_g,
               float* __restrict__ Cf, int ntp)
{
    constexpr int CPW = TN / 64;
    constexpr int XCELLS = 2 * 4 * 128;
    constexpr int WCELLS = 2 * 4 * TN;
    __shared__ ushort smem[(XCELLS + WCELLS) * 8];
    ushort* sX = smem;
    ushort* sW = smem + XCELLS * 8;

    const int tid = threadIdx.x;
    const int w = tid >> 6, l = tid & 63;
    const int wr = w >> 2;
    const int wc = w & 3;
    const int seg = l >> 4, lr = l & 15;
    const int row0 = blockIdx.x * 128;
    const bool g = (row0 >= ntp);
    const ushort* __restrict__ WThi = g ? WThi_g : WThi_t;
    const ushort* __restrict__ WTlo = g ? WTlo_g : WTlo_t;

    float4v acc[4][CPW];
#pragma unroll
    for (int i = 0; i < 4; ++i)
#pragma unroll
        for (int j = 0; j < CPW; ++j) {
            float4v z = {0.f, 0.f, 0.f, 0.f};
            acc[i][j] = z;
        }

    for (int kc = 0; kc < 128; kc += 32) {
        __syncthreads();
#pragma unroll
        for (int t = 0; t < XCELLS / 512; ++t) {
            const int cbase = (w * (XCELLS / 512) + t) * 64;
            const int c = cbase + l;
            const int plane = c >> 9, rem = c & 511, sg = rem >> 7, r = rem & 127;
            const ushort* srcp = plane ? Xlo : Xhi;
            gload_lds16(&srcp[(size_t)(row0 + r) * XS + kc + sg * 8],
                        (char*)sX + (size_t)cbase * 16);
        }
#pragma unroll
        for (int t = 0; t < WCELLS / 512; ++t) {
            const int cbase = (w * (WCELLS / 512) + t) * 64;
            const int c = cbase + l;
            const int plane = (c >= WCELLS / 2) ? 1 : 0;
            const int rem = c - plane * (WCELLS / 2);
            const int sg = rem / TN, col = rem % TN;
            const ushort* srcp = plane ? WTlo : WThi;
            gload_lds16(&srcp[(size_t)col * 128 + kc + sg * 8],
                        (char*)sW + (size_t)cbase * 16);
        }
        __syncthreads();

        short8v ah[4], al[4];
#pragma unroll
        for (int i = 0; i < 4; ++i) {
            const int off = (seg * 128 + wr * 64 + i * 16 + lr) * 8;
            ah[i] = *(const short8v*)&sX[off];
            al[i] = *(const short8v*)&sX[(XCELLS / 2) * 8 + off];
        }
#pragma unroll
        for (int j = 0; j < CPW; ++j) {
            const int col = (wc * CPW + j) * 16 + lr;
            const int off = (seg * TN + col) * 8;
            short8v bh = *(const short8v*)&sW[off];
            short8v bl = *(const short8v*)&sW[(WCELLS / 2) * 8 + off];
#pragma unroll
            for (int i = 0; i < 4; ++i) {
                acc[i][j] = __builtin_amdgcn_mfma_f32_16x16x32_bf16(ah[i], bh, acc[i][j], 0, 0, 0);
                acc[i][j] = __builtin_amdgcn_mfma_f32_16x16x32_bf16(ah[i], bl, acc[i][j], 0, 0, 0);
                acc[i][j] = __builtin_amdgcn_mfma_f32_16x16x32_bf16(al[i], bh, acc[i][j], 0, 0, 0);
            }
        }
    }

#pragma unroll
    for (int i = 0; i < 4; ++i) {
#pragma unroll
        for (int j = 0; j < CPW; ++j) {
            const int gcol = (wc * CPW + j) * 16 + lr;
#pragma unroll
            for (int r = 0; r < 4; ++r) {
                const int grow = row0 + wr * 64 + i * 16 + seg * 4 + r;
                Cf[(size_t)grow * TN + gcol] = acc[i][j][r];
            }
        }
    }
}

// ============ fused gather + lin: h' = relu(gather(AB) @ lin + b) -> left half hi/lo ============
// Phase 1: 16 groups x 32 lanes gather 8 nodes each; aggr -> LDS in A-frag layout,
//   cell(chunk,plane,sg,slot) with slot = row ^ ((chunk*4+sg)&7)  (writes 2-way-free).
// Phase 2: lin GEMM, A from aggr LDS, W staged per chunk (16 KB). Same MFMA order as R11.
__global__ __launch_bounds__(512, 4)
void gather_lin(float* __restrict__ buf,
                const float* __restrict__ mbt, const float* __restrict__ mbg,
                const int* __restrict__ rowptr, const int* __restrict__ deg,
                const int* __restrict__ csr_src,
                const ushort* __restrict__ LThi_t, const ushort* __restrict__ LTlo_t,
                const ushort* __restrict__ LThi_g, const ushort* __restrict__ LTlo_g,
                const float* __restrict__ lbt, const float* __restrict__ lbg,
                ushort* __restrict__ Chi, ushort* __restrict__ Clo,
                int ntp)
{
    extern __shared__ ushort smem[];            // 81920 B dynamic
    ushort* aggr = smem;                        // 64 KB: 4096 cells of 16 B
    ushort* sW   = smem + 32768;                // 16 KB: 1024 cells

    const int tid = threadIdx.x;
    const int row0 = blockIdx.x * 128;
    const bool g = (row0 >= ntp);
    const float* mb = g ? mbg : mbt;
    const ushort* __restrict__ LThi = g ? LThi_g : LThi_t;
    const ushort* __restrict__ LTlo = g ? LTlo_g : LTlo_t;
    const float* lb = g ? lbg : lbt;

    // ---- phase 1: gather ----
    {
        const int grp = tid >> 5, lane = tid & 31;
        const int f = lane * 4;
        const int chunk = f >> 5, sg = (f >> 3) & 3;
        const int s8 = (f >> 3) & 7;
        const int halfb = (lane & 1) * 8;       // byte offset within 16B cell
        const float4 m = *(const float4*)&mb[f];
#pragma unroll 1
        for (int it = 0; it < 8; ++it) {
            const int r = grp * 8 + it;
            const int v = row0 + r;
            float4 a = *(const float4*)&buf[(size_t)v * 256 + f];
            const float ax = a.x + m.x, ay = a.y + m.y, az = a.z + m.z, aw = a.w + m.w;
            float4 acc = {0.f, 0.f, 0.f, 0.f};
            const int start = rowptr[v];
            const int cnt = deg[v];
            for (int i = 0; i < cnt; ++i) {
                int s = csr_src[start + i];
                float4 b = *(const float4*)&buf[(size_t)s * 256 + 128 + f];
                acc.x += fmaxf(ax + b.x, 0.f);
                acc.y += fmaxf(ay + b.y, 0.f);
                acc.z += fmaxf(az + b.z, 0.f);
                acc.w += fmaxf(aw + b.w, 0.f);
            }
            ushort4 h4, l4;
            ushort* hp = (ushort*)&h4; ushort* lp = (ushort*)&l4;
            split_bf(acc.x, hp[0], lp[0]);
            split_bf(acc.y, hp[1], lp[1]);
            split_bf(acc.z, hp[2], lp[2]);
            split_bf(acc.w, hp[3], lp[3]);
            const int slot = r ^ s8;
            *(ushort4*)((char*)aggr + ((size_t)((chunk * 2 + 0) * 512 + sg * 128 + slot)) * 16 + halfb) = h4;
            *(ushort4*)((char*)aggr + ((size_t)((chunk * 2 + 1) * 512 + sg * 128 + slot)) * 16 + halfb) = l4;
        }
    }

    // ---- phase 2: lin GEMM ----
    const int w = tid >> 6, l = tid & 63;
    const int wr = w >> 2, wc = w & 3;
    const int seg = l >> 4, lr = l & 15;
    constexpr int CPW = 2;                      // TN=128

    float4v acc[4][CPW];
#pragma unroll
    for (int i = 0; i < 4; ++i)
#pragma unroll
        for (int j = 0; j < CPW; ++j) {
            float4v z = {0.f, 0.f, 0.f, 0.f};
            acc[i][j] = z;
        }

    for (int kc = 0; kc < 128; kc += 32) {
        __syncthreads();                        // phase-1 done / prev chunk sW reads done
#pragma unroll
        for (int t = 0; t < 2; ++t) {
            const int cbase = (w * 2 + t) * 64;
            const int c = cbase + l;
            const int plane = c >> 9, rem = c & 511, sgw = rem >> 7, col = rem & 127;
            const ushort* srcp = plane ? LTlo : LThi;
            gload_lds16(&srcp[(size_t)col * 128 + kc + sgw * 8],
                        (char*)sW + (size_t)cbase * 16);
        }
        __syncthreads();

        const int chunk = kc >> 5;
        const int s8 = ((kc >> 3) + seg) & 7;
        short8v ah[4], al[4];
#pragma unroll
        for (int i = 0; i < 4; ++i) {
            const int row = wr * 64 + i * 16 + lr;
            const int slot = row ^ s8;
            ah[i] = *(const short8v*)&aggr[((size_t)(chunk * 2 + 0) * 512 + seg * 128 + slot) * 8];
            al[i] = *(const short8v*)&aggr[((size_t)(chunk * 2 + 1) * 512 + seg * 128 + slot) * 8];
        }
#pragma unroll
        for (int j = 0; j < CPW; ++j) {
            const int col = (wc * CPW + j) * 16 + lr;
            short8v bh = *(const short8v*)&sW[((size_t)0 * 512 + seg * 128 + col) * 8];
            short8v bl = *(const short8v*)&sW[((size_t)1 * 512 + seg * 128 + col) * 8];
#pragma unroll
            for (int i = 0; i < 4; ++i) {
                acc[i][j] = __builtin_amdgcn_mfma_f32_16x16x32_bf16(ah[i], bh, acc[i][j], 0, 0, 0);
                acc[i][j] = __builtin_amdgcn_mfma_f32_16x16x32_bf16(ah[i], bl, acc[i][j], 0, 0, 0);
                acc[i][j] = __builtin_amdgcn_mfma_f32_16x16x32_bf16(al[i], bh, acc[i][j], 0, 0, 0);
            }
        }
    }

    // epilogue -> left half hi/lo (stride 512)
#pragma unroll
    for (int i = 0; i < 4; ++i) {
#pragma unroll
        for (int j = 0; j < CPW; ++j) {
            const int gcol = (wc * CPW + j) * 16 + lr;
            const float bv = lb[gcol];
#pragma unroll
            for (int r = 0; r < 4; ++r) {
                const int grow = row0 + wr * 64 + i * 16 + seg * 4 + r;
                float v = fmaxf(acc[i][j][r] + bv, 0.f);
                ushort hi, lo;
                split_bf(v, hi, lo);
                Chi[(size_t)grow * 512 + gcol] = hi;
                Clo[(size_t)grow * 512 + gcol] = lo;
            }
        }
    }
}

// ============ f32 vector GEMM for input projection (K=32/64) -> hi/lo @ stride CS ============
template<int K>
__global__ __launch_bounds__(256)
void gemm_rt(const float* __restrict__ X, const float* __restrict__ W,
             const float* __restrict__ bias,
             ushort* __restrict__ Chi, ushort* __restrict__ Clo, int CS, int n)
{
    constexpr int TN = 128;
    constexpr int KC = 32;
    __shared__ float sXT[KC][128];
    __shared__ float sW[KC][TN];

    const int tid  = threadIdx.x;
    const int row0 = blockIdx.x * 128;
    const int rows = min(128, n - row0);
    if (rows <= 0) return;
    const int cg = tid % 16;
    const int rg = tid / 16;

    float acc[8][8] = {};

    for (int kc = 0; kc < K; kc += KC) {
        __syncthreads();
        for (int i = tid; i < KC * (TN / 4); i += 256) {
            int k = i / (TN / 4), c4 = i % (TN / 4);
            ((float4*)sW[k])[c4] = *(const float4*)&W[(size_t)(kc + k) * TN + c4 * 4];
        }
        for (int i = tid; i < (KC / 4) * 128; i += 256) {
            int r = i & 127, k4 = i >> 7;
            float4 v = {0.f, 0.f, 0.f, 0.f};
            if (r < rows) v = *(const float4*)&X[(size_t)(row0 + r) * K + kc + k4 * 4];
            sXT[k4 * 4 + 0][r] = v.x;
            sXT[k4 * 4 + 1][r] = v.y;
            sXT[k4 * 4 + 2][r] = v.z;
            sXT[k4 * 4 + 3][r] = v.w;
        }
        __syncthreads();
#pragma unroll 4
        for (int k = 0; k < KC; ++k) {
            float wv[8], xv[8];
            *(float4*)&wv[0] = *(const float4*)&sW[k][cg * 4];
            *(float4*)&wv[4] = *(const float4*)&sW[k][cg * 4 + 64];
            *(float4*)&xv[0] = *(const float4*)&sXT[k][rg * 4];
            *(float4*)&xv[4] = *(const float4*)&sXT[k][rg * 4 + 64];
#pragma unroll
            for (int i = 0; i < 8; ++i)
#pragma unroll
                for (int j = 0; j < 8; ++j)
                    acc[i][j] += xv[i] * wv[j];
        }
    }
#pragma unroll
    for (int i = 0; i < 8; ++i) {
        const int r = (i < 4) ? rg * 4 + i : 64 + rg * 4 + (i - 4);
        if (r < rows) {
#pragma unroll
            for (int half = 0; half < 2; ++half) {
                const int c = cg * 4 + half * 64;
                ushort4 h4, l4;
                ushort* hp = (ushort*)&h4; ushort* lp = (ushort*)&l4;
#pragma unroll
                for (int j = 0; j < 4; ++j) {
                    float v = fmaxf(acc[i][half * 4 + j] + bias[c + j], 0.f);
                    split_bf(v, hp[j], lp[j]);
                }
                *(ushort4*)&Chi[(size_t)(row0 + r) * CS + c] = h4;
                *(ushort4*)&Clo[(size_t)(row0 + r) * CS + c] = l4;
            }
        }
    }
}

// ============ weight transpose + split, both encoders ============
__global__ __launch_bounds__(256)
void tconv_all(const float* __restrict__ MWt, const float* __restrict__ MWg,
               const float* __restrict__ LWt, const float* __restrict__ LWg,
               ushort* __restrict__ WThi, ushort* __restrict__ WTlo,
               ushort* __restrict__ LThi, ushort* __restrict__ LTlo)
{
    int idx = blockIdx.x * 256 + threadIdx.x;
    if (idx < 2 * 98304) {
        int enc = idx / 98304, r2 = idx % 98304;
        int l = r2 >> 15, r = r2 & 32767;
        int row = r >> 7, c = r & 127;
        int k, col;
        if (row < 128) { k = row; col = c; } else { k = row - 128; col = 128 + c; }
        const float* src = enc ? MWg : MWt;
        ushort hi, lo;
        split_bf(src[r2], hi, lo);
        size_t o = (size_t)(enc * 3 + l) * 32768 + (size_t)col * 128 + k;
        WThi[o] = hi; WTlo[o] = lo;
    } else {
        int j = idx - 2 * 98304;
        if (j >= 2 * 49152) return;
        int enc = j / 49152, r2 = j % 49152;
        int l = r2 >> 14, r = r2 & 16383;
        int k = r >> 7, nn = r & 127;
        const float* src = enc ? LWg : LWt;
        ushort hi, lo;
        split_bf(src[r2], hi, lo);
        size_t o = (size_t)(enc * 3 + l) * 16384 + (size_t)nn * 128 + k;
        LThi[o] = hi; LTlo[o] = lo;
    }
}

// ============ CSR build (unified node space) ============
__global__ __launch_bounds__(256)
void hist_all(const int* __restrict__ tei, const int* __restrict__ gei,
              int et, int eg, int ntp, int* __restrict__ deg)
{
    int i = blockIdx.x * 256 + threadIdx.x;
    if (i < et) atomicAdd(&deg[tei[et + i]], 1);
    else if (i < et + eg) atomicAdd(&deg[gei[eg + (i - et)] + ntp], 1);
}

__global__ __launch_bounds__(256)
void scan_stage1(const int* __restrict__ in, int* __restrict__ excl,
                 int* __restrict__ partial, int n)
{
    const int tid = threadIdx.x;
    const int base = blockIdx.x * 1024 + tid * 4;
    int v[4];
    int s = 0;
#pragma unroll
    for (int i = 0; i < 4; ++i) {
        int t = (base + i < n) ? in[base + i] : 0;
        v[i] = s; s += t;
    }
    __shared__ int warpsum[4];
    const int lane = tid & 63, wid = tid >> 6;
    int pre = s;
#pragma unroll
    for (int off = 1; off < 64; off <<= 1) {
        int t = __shfl_up(pre, off);
        if (lane >= off) pre += t;
    }
    if (lane == 63) warpsum[wid] = pre;
    __syncthreads();
    int wo = 0;
    for (int w = 0; w < wid; ++w) wo += warpsum[w];
    const int thread_excl = wo + pre - s;
#pragma unroll
    for (int i = 0; i < 4; ++i)
        if (base + i < n) excl[base + i] = thread_excl + v[i];
    if (partial && tid == 255) partial[blockIdx.x] = wo + pre;
}

__global__ __launch_bounds__(256)
void scan_stage2(int* __restrict__ partial, int nb)
{
    __shared__ int tmp[256];
    const int tid = threadIdx.x;
    int v = (tid < nb) ? partial[tid] : 0;
    tmp[tid] = v;
    __syncthreads();
    for (int off = 1; off < 256; off <<= 1) {
        int t = (tid >= off) ? tmp[tid - off] : 0;
        __syncthreads();
        tmp[tid] += t;
        __syncthreads();
    }
    if (tid < nb) partial[tid] = tmp[tid] - v;
}

__global__ __launch_bounds__(256)
void scan_stage3(int* __restrict__ excl, const int* __restrict__ partial, int n)
{
    const int base = blockIdx.x * 1024 + threadIdx.x * 4;
    const int p = partial[blockIdx.x];
#pragma unroll
    for (int i = 0; i < 4; ++i)
        if (base + i < n) excl[base + i] += p;
}

__global__ __launch_bounds__(256)
void csr_fill_all(const int* __restrict__ tei, const int* __restrict__ gei,
                  int et, int eg, int ntp,
                  const int* __restrict__ rowptr, int* __restrict__ cursor,
                  int* __restrict__ csr_src)
{
    int e = blockIdx.x * 256 + threadIdx.x;
    int s, d;
    if (e < et) { s = tei[e]; d = tei[et + e]; }
    else if (e < et + eg) { int i = e - et; s = gei[i] + ntp; d = gei[eg + i] + ntp; }
    else return;
    int pos = atomicAdd(&cursor[d], 1);
    csr_src[rowptr[d] + pos] = s;
}

// ============ batch ranges via binary search (batch sorted) ============
__global__ __launch_bounds__(256)
void rpb_search(const int* __restrict__ batch_t, int nt,
                const int* __restrict__ batch_g, int ng, int* __restrict__ rpb)
{
    int t = blockIdx.x * 256 + threadIdx.x;
    if (t >= 2 * (NGRAPHS + 1)) return;
    const int enc = t / (NGRAPHS + 1);
    const int b = t % (NGRAPHS + 1);
    const int* batch = enc ? batch_g : batch_t;
    const int n = enc ? ng : nt;
    int lo = 0, hi = n;
    while (lo < hi) { int mid = (lo + hi) >> 1; if (batch[mid] < b) lo = mid + 1; else hi = mid; }
    rpb[t] = lo;
}

// ============ pooling (LEFT-half h, per-graph contiguous ranges) ============
__global__ __launch_bounds__(128)
void pool_mean(const ushort* __restrict__ U, const int* __restrict__ rpb,
               int ntp, float* __restrict__ fused)
{
    const int bid = blockIdx.x;
    const int enc = bid >> 10, b = bid & 1023;
    const int f = threadIdx.x;
    const int base_i = enc * (NGRAPHS + 1) + b;
    const int start = rpb[base_i];
    const int c = rpb[base_i + 1] - start;
    const int row0 = start + (enc ? ntp : 0);
    float acc = 0.f;
    for (int i = 0; i < c; ++i) {
        size_t o = (size_t)(row0 + i) * 512 + f;
        acc += bf2f(U[o]) + bf2f(U[o + 128]);
    }
    fused[(size_t)b * 256 + enc * 128 + f] = acc / fmaxf((float)c, 1.0f);
}

// ============ head ============
__global__ __launch_bounds__(128)
void head_kernel(const float* __restrict__ fused,
                 const float* __restrict__ muw, const float* __restrict__ mub,
                 const float* __restrict__ lvw, const float* __restrict__ lvb,
                 float* __restrict__ mu, float* __restrict__ lv)
{
    __shared__ float sf[2 * HIDDEN];
    const int b = blockIdx.x;
    const int t = threadIdx.x;
    sf[t] = fused[(size_t)b * 256 + t];
    sf[t + 128] = fused[(size_t)b * 256 + t + 128];
    __syncthreads();
    if (t < ZDIM) {
        float accm = mub[t], accl = lvb[t];
        for (int k = 0; k < 2 * HIDDEN; ++k) {
            float fv = sf[k];
            accm += fv * muw[(size_t)k * ZDIM + t];
            accl += fv * lvw[(size_t)k * ZDIM + t];
        }
        mu[(size_t)b * ZDIM + t] = accm;
        lv[(size_t)b * ZDIM + t] = accl;
    }
}

extern "C" void kernel_launch(void* const* d_in, const int* in_sizes, int n_in,
                              void* d_out, int out_size, void* d_ws, size_t ws_size,
                              hipStream_t stream)
{
    const float* tree_x   = (const float*)d_in[0];
    const int*   tree_ei  = (const int*)d_in[1];
    const float* graph_x  = (const float*)d_in[2];
    const int*   graph_ei = (const int*)d_in[3];
    const int*   batch_t  = (const int*)d_in[4];
    const int*   batch_g  = (const int*)d_in[5];
    const float* t_proj_w = (const float*)d_in[6];
    const float* t_proj_b = (const float*)d_in[7];
    const float* t_msg_w  = (const float*)d_in[8];
    const float* t_msg_b  = (const float*)d_in[9];
    const float* t_lin_w  = (const float*)d_in[10];
    const float* t_lin_b  = (const float*)d_in[11];
    const float* g_proj_w = (const float*)d_in[12];
    const float* g_proj_b = (const float*)d_in[13];
    const float* g_msg_w  = (const float*)d_in[14];
    const float* g_msg_b  = (const float*)d_in[15];
    const float* g_lin_w  = (const float*)d_in[16];
    const float* g_lin_b  = (const float*)d_in[17];
    const float* mu_w     = (const float*)d_in[18];
    const float* mu_b     = (const float*)d_in[19];
    const float* lv_w     = (const float*)d_in[20];
    const float* lv_b     = (const float*)d_in[21];

    const int n_tree  = in_sizes[0] / 64;
    const int e_tree  = in_sizes[1] / 2;
    const int n_graph = in_sizes[2] / 32;
    const int e_graph = in_sizes[3] / 2;
    const int E_tot   = e_tree + e_graph;

    const int ntp  = ((n_tree + 127) / 128) * 128;
    const int npg  = ((n_graph + 127) / 128) * 128;
    const int NTOT = ntp + npg;
    const int GB   = NTOT / 128;

    float* out    = (float*)d_out;
    float* mu_out = out;
    float* lv_out = out + (size_t)NGRAPHS * ZDIM;
    float* fused  = out + (size_t)2 * NGRAPHS * ZDIM;

    // ---- workspace carve ----
    char* base = (char*)d_ws;
    float*  buf  = (float*)base;  base += (size_t)NTOT * 256 * sizeof(float);
    ushort* U    = (ushort*)buf;
    ushort* WThi = (ushort*)base; base += (size_t)6 * 32768 * sizeof(ushort);
    ushort* WTlo = (ushort*)base; base += (size_t)6 * 32768 * sizeof(ushort);
    ushort* LThi = (ushort*)base; base += (size_t)6 * 16384 * sizeof(ushort);
    ushort* LTlo = (ushort*)base; base += (size_t)6 * 16384 * sizeof(ushort);
    int* deg     = (int*)base;    base += (size_t)NTOT * sizeof(int);
    int* cursor  = (int*)base;    base += (size_t)NTOT * sizeof(int);
    int* rowptr  = (int*)base;    base += (size_t)NTOT * sizeof(int);
    int* csr_src = (int*)base;    base += (size_t)E_tot * sizeof(int);
    int* partial = (int*)base;    base += 256 * sizeof(int);
    int* rpb     = (int*)base;

    const int nb = (NTOT + 1023) / 1024;

    // ---- CSR build (unified) ----
    hipMemsetAsync(deg, 0, (size_t)2 * NTOT * sizeof(int), stream);
    hist_all<<<(E_tot + 255) / 256, 256, 0, stream>>>(tree_ei, graph_ei, e_tree, e_graph, ntp, deg);
    scan_stage1<<<nb, 256, 0, stream>>>(deg, rowptr, partial, NTOT);
    scan_stage2<<<1, 256, 0, stream>>>(partial, nb);
    scan_stage3<<<nb, 256, 0, stream>>>(rowptr, partial, NTOT);
    csr_fill_all<<<(E_tot + 255) / 256, 256, 0, stream>>>(tree_ei, graph_ei, e_tree, e_graph,
                                                          ntp, rowptr, cursor, csr_src);
    rpb_search<<<(2 * (NGRAPHS + 1) + 255) / 256, 256, 0, stream>>>(batch_t, n_tree,
                                                                    batch_g, n_graph, rpb);
    tconv_all<<<(2 * 98304 + 2 * 49152 + 255) / 256, 256, 0, stream>>>(
        t_msg_w, g_msg_w, t_lin_w, g_lin_w, WThi, WTlo, LThi, LTlo);

    // ---- input projections -> LEFT-half h hi/lo ----
    gemm_rt<64><<<(n_tree + 127) / 128, 256, 0, stream>>>(
        tree_x, t_proj_w, t_proj_b, U, U + 128, 512, n_tree);
    gemm_rt<32><<<(n_graph + 127) / 128, 256, 0, stream>>>(
        graph_x, g_proj_w, g_proj_b,
        U + (size_t)ntp * 512, U + 128 + (size_t)ntp * 512, 512, n_graph);

    // ---- fused layer loop ----
    for (int l = 0; l < NLAYERS; ++l) {
        // AB = h @ [Wtop|Wbot] : LEFT-half X -> full-row f32 (in place per block)
        gemm_mfma<256><<<GB, 512, 0, stream>>>(
            U, U + 128, 512,
            WThi + (size_t)l * 32768, WTlo + (size_t)l * 32768,
            WThi + (size_t)(3 + l) * 32768, WTlo + (size_t)(3 + l) * 32768,
            buf, ntp);
        // h' = relu(gather(AB) @ lin + b) -> LEFT-half hi/lo (aggr never touches HBM)
        gather_lin<<<GB, 512, 81920, stream>>>(
            buf, t_msg_b + (size_t)l * HIDDEN, g_msg_b + (size_t)l * HIDDEN,
            rowptr, deg, csr_src,
            LThi + (size_t)l * 16384, LTlo + (size_t)l * 16384,
            LThi + (size_t)(3 + l) * 16384, LTlo + (size_t)(3 + l) * 16384,
            t_lin_b + (size_t)l * HIDDEN, g_lin_b + (size_t)l * HIDDEN,
            U, U + 128, ntp);
    }

    pool_mean<<<2 * NGRAPHS, 128, 0, stream>>>(U, rpb, ntp, fused);
    head_kernel<<<NGRAPHS, 128, 0, stream>>>(fused, mu_w, mu_b, lv_w, lv_b, mu_out, lv_out);
}

// Round 13
// 597.379 us; speedup vs baseline: 1.7523x; 1.1110x over previous
//
#include <hip/hip_runtime.h>

#define HIDDEN 128
#define ZDIM 56
#define NLAYERS 3
#define NGRAPHS 1024

typedef __attribute__((ext_vector_type(8))) short short8v;
typedef __attribute__((ext_vector_type(4))) float float4v;

__device__ __forceinline__ ushort f2bf(float v) {
    union { float f; unsigned u; } x; x.f = v;
    unsigned r = x.u + 0x7fffu + ((x.u >> 16) & 1u);   // RNE
    return (ushort)(r >> 16);
}
__device__ __forceinline__ float bf2f(ushort h) {
    union { unsigned u; float f; } x; x.u = ((unsigned)h) << 16;
    return x.f;
}
__device__ __forceinline__ void split_bf(float v, ushort& hi, ushort& lo) {
    hi = f2bf(v);
    lo = f2bf(v - bf2f(hi));
}
__device__ __forceinline__ void gload_lds16(const void* g, void* l) {
    __builtin_amdgcn_global_load_lds(
        (const __attribute__((address_space(1))) unsigned int*)g,
        (__attribute__((address_space(3))) unsigned int*)l, 16, 0, 0);
}

// ================= unified row-space layout =================
// buf = f32 [NTOT][256] (1024 B/row). Per row v:
//   left  half bytes [0,512):   h hi/lo (proj & fused-lin out) -> A part of AB (msg out)
//   right half bytes [512,1024): B part of AB (msg out); read cross-block by gather
// ushort view U: row stride 512; left hi @0, left lo @128.
// Tree rows [0, ntp); graph rows [ntp, NTOT). Pad rows: finite garbage, deg=0.

// ============ split-bf16 MFMA msg GEMM (R11 structure): AB = h @ [Wtop|Wbot] ============
template<int TN>
__global__ __launch_bounds__(512, 4)
void gemm_mfma(const ushort* __restrict__ Xhi, const ushort* __restrict__ Xlo, int XS,
               const ushort* __restrict__ WThi_t, const ushort* __restrict__ WTlo_t,
               const ushort* __restrict__ WThi_g, const ushort* __restrict__ WTlo_g,
               float* __restrict__ Cf, int ntp)
{
    constexpr int CPW = TN / 64;
    constexpr int XCELLS = 2 * 4 * 128;
    constexpr int WCELLS = 2 * 4 * TN;
    __shared__ ushort smem[(XCELLS + WCELLS) * 8];
    ushort* sX = smem;
    ushort* sW = smem + XCELLS * 8;

    const int tid = threadIdx.x;
    const int w = tid >> 6, l = tid & 63;
    const int wr = w >> 2;
    const int wc = w & 3;
    const int seg = l >> 4, lr = l & 15;
    const int row0 = blockIdx.x * 128;
    const bool g = (row0 >= ntp);
    const ushort* __restrict__ WThi = g ? WThi_g : WThi_t;
    const ushort* __restrict__ WTlo = g ? WTlo_g : WTlo_t;

    float4v acc[4][CPW];
#pragma unroll
    for (int i = 0; i < 4; ++i)
#pragma unroll
        for (int j = 0; j < CPW; ++j) {
            float4v z = {0.f, 0.f, 0.f, 0.f};
            acc[i][j] = z;
        }

    for (int kc = 0; kc < 128; kc += 32) {
        __syncthreads();
#pragma unroll
        for (int t = 0; t < XCELLS / 512; ++t) {
            const int cbase = (w * (XCELLS / 512) + t) * 64;
            const int c = cbase + l;
            const int plane = c >> 9, rem = c & 511, sg = rem >> 7, r = rem & 127;
            const ushort* srcp = plane ? Xlo : Xhi;
            gload_lds16(&srcp[(size_t)(row0 + r) * XS + kc + sg * 8],
                        (char*)sX + (size_t)cbase * 16);
        }
#pragma unroll
        for (int t = 0; t < WCELLS / 512; ++t) {
            const int cbase = (w * (WCELLS / 512) + t) * 64;
            const int c = cbase + l;
            const int plane = (c >= WCELLS / 2) ? 1 : 0;
            const int rem = c - plane * (WCELLS / 2);
            const int sg = rem / TN, col = rem % TN;
            const ushort* srcp = plane ? WTlo : WThi;
            gload_lds16(&srcp[(size_t)col * 128 + kc + sg * 8],
                        (char*)sW + (size_t)cbase * 16);
        }
        __syncthreads();

        short8v ah[4], al[4];
#pragma unroll
        for (int i = 0; i < 4; ++i) {
            const int off = (seg * 128 + wr * 64 + i * 16 + lr) * 8;
            ah[i] = *(const short8v*)&sX[off];
            al[i] = *(const short8v*)&sX[(XCELLS / 2) * 8 + off];
        }
#pragma unroll
        for (int j = 0; j < CPW; ++j) {
            const int col = (wc * CPW + j) * 16 + lr;
            const int off = (seg * TN + col) * 8;
            short8v bh = *(const short8v*)&sW[off];
            short8v bl = *(const short8v*)&sW[(WCELLS / 2) * 8 + off];
#pragma unroll
            for (int i = 0; i < 4; ++i) {
                acc[i][j] = __builtin_amdgcn_mfma_f32_16x16x32_bf16(ah[i], bh, acc[i][j], 0, 0, 0);
                acc[i][j] = __builtin_amdgcn_mfma_f32_16x16x32_bf16(ah[i], bl, acc[i][j], 0, 0, 0);
                acc[i][j] = __builtin_amdgcn_mfma_f32_16x16x32_bf16(al[i], bh, acc[i][j], 0, 0, 0);
            }
        }
    }

#pragma unroll
    for (int i = 0; i < 4; ++i) {
#pragma unroll
        for (int j = 0; j < CPW; ++j) {
            const int gcol = (wc * CPW + j) * 16 + lr;
#pragma unroll
            for (int r = 0; r < 4; ++r) {
                const int grow = row0 + wr * 64 + i * 16 + seg * 4 + r;
                Cf[(size_t)grow * TN + gcol] = acc[i][j][r];
            }
        }
    }
}

// ============ fused gather + lin: h' = relu(gather(AB) @ lin + b) -> left half hi/lo ============
// Phase 1: 16 groups x 32 lanes gather 8 nodes each, 4-way edge-unrolled for MLP;
//   aggr -> LDS in A-frag layout, slot = row ^ ((chunk*4+sg)&7).
// Phase 2: lin GEMM, A from aggr LDS, W staged per chunk. Same MFMA order as R11.
__global__ __launch_bounds__(512, 4)
void gather_lin(float* __restrict__ buf,
                const float* __restrict__ mbt, const float* __restrict__ mbg,
                const int* __restrict__ rowptr, const int* __restrict__ deg,
                const int* __restrict__ csr_src,
                const ushort* __restrict__ LThi_t, const ushort* __restrict__ LTlo_t,
                const ushort* __restrict__ LThi_g, const ushort* __restrict__ LTlo_g,
                const float* __restrict__ lbt, const float* __restrict__ lbg,
                ushort* __restrict__ Chi, ushort* __restrict__ Clo,
                int ntp)
{
    extern __shared__ ushort smem[];            // 81920 B dynamic
    ushort* aggr = smem;                        // 64 KB
    ushort* sW   = smem + 32768;                // 16 KB

    const int tid = threadIdx.x;
    const int row0 = blockIdx.x * 128;
    const bool g = (row0 >= ntp);
    const float* mb = g ? mbg : mbt;
    const ushort* __restrict__ LThi = g ? LThi_g : LThi_t;
    const ushort* __restrict__ LTlo = g ? LTlo_g : LTlo_t;
    const float* lb = g ? lbg : lbt;

    // ---- phase 1: gather (4-way edge-unrolled) ----
    {
        const int grp = tid >> 5, lane = tid & 31;
        const int f = lane * 4;
        const int chunk = f >> 5, sg = (f >> 3) & 3;
        const int s8 = (f >> 3) & 7;
        const int halfb = (lane & 1) * 8;
        const float4 m = *(const float4*)&mb[f];
        const float* __restrict__ bufB = buf + 128 + f;
#pragma unroll 1
        for (int it = 0; it < 8; ++it) {
            const int r = grp * 8 + it;
            const int v = row0 + r;
            float4 a = *(const float4*)&buf[(size_t)v * 256 + f];
            const float ax = a.x + m.x, ay = a.y + m.y, az = a.z + m.z, aw = a.w + m.w;
            float4 ac0 = {0.f, 0.f, 0.f, 0.f};
            float4 ac1 = {0.f, 0.f, 0.f, 0.f};
            float4 ac2 = {0.f, 0.f, 0.f, 0.f};
            float4 ac3 = {0.f, 0.f, 0.f, 0.f};
            const int start = rowptr[v];
            const int cnt = deg[v];
            int i = 0;
            for (; i + 4 <= cnt; i += 4) {
                const int s0 = csr_src[start + i];
                const int s1 = csr_src[start + i + 1];
                const int s2 = csr_src[start + i + 2];
                const int s3 = csr_src[start + i + 3];
                float4 b0 = *(const float4*)&bufB[(size_t)s0 * 256];
                float4 b1 = *(const float4*)&bufB[(size_t)s1 * 256];
                float4 b2 = *(const float4*)&bufB[(size_t)s2 * 256];
                float4 b3 = *(const float4*)&bufB[(size_t)s3 * 256];
                ac0.x += fmaxf(ax + b0.x, 0.f); ac0.y += fmaxf(ay + b0.y, 0.f);
                ac0.z += fmaxf(az + b0.z, 0.f); ac0.w += fmaxf(aw + b0.w, 0.f);
                ac1.x += fmaxf(ax + b1.x, 0.f); ac1.y += fmaxf(ay + b1.y, 0.f);
                ac1.z += fmaxf(az + b1.z, 0.f); ac1.w += fmaxf(aw + b1.w, 0.f);
                ac2.x += fmaxf(ax + b2.x, 0.f); ac2.y += fmaxf(ay + b2.y, 0.f);
                ac2.z += fmaxf(az + b2.z, 0.f); ac2.w += fmaxf(aw + b2.w, 0.f);
                ac3.x += fmaxf(ax + b3.x, 0.f); ac3.y += fmaxf(ay + b3.y, 0.f);
                ac3.z += fmaxf(az + b3.z, 0.f); ac3.w += fmaxf(aw + b3.w, 0.f);
            }
            for (; i < cnt; ++i) {
                const int s0 = csr_src[start + i];
                float4 b0 = *(const float4*)&bufB[(size_t)s0 * 256];
                ac0.x += fmaxf(ax + b0.x, 0.f); ac0.y += fmaxf(ay + b0.y, 0.f);
                ac0.z += fmaxf(az + b0.z, 0.f); ac0.w += fmaxf(aw + b0.w, 0.f);
            }
            float4 acc;
            acc.x = (ac0.x + ac1.x) + (ac2.x + ac3.x);
            acc.y = (ac0.y + ac1.y) + (ac2.y + ac3.y);
            acc.z = (ac0.z + ac1.z) + (ac2.z + ac3.z);
            acc.w = (ac0.w + ac1.w) + (ac2.w + ac3.w);
            ushort4 h4, l4;
            ushort* hp = (ushort*)&h4; ushort* lp = (ushort*)&l4;
            split_bf(acc.x, hp[0], lp[0]);
            split_bf(acc.y, hp[1], lp[1]);
            split_bf(acc.z, hp[2], lp[2]);
            split_bf(acc.w, hp[3], lp[3]);
            const int slot = r ^ s8;
            *(ushort4*)((char*)aggr + ((size_t)((chunk * 2 + 0) * 512 + sg * 128 + slot)) * 16 + halfb) = h4;
            *(ushort4*)((char*)aggr + ((size_t)((chunk * 2 + 1) * 512 + sg * 128 + slot)) * 16 + halfb) = l4;
        }
    }

    // ---- phase 2: lin GEMM ----
    const int w = tid >> 6, l = tid & 63;
    const int wr = w >> 2, wc = w & 3;
    const int seg = l >> 4, lr = l & 15;
    constexpr int CPW = 2;                      // TN=128

    float4v acc[4][CPW];
#pragma unroll
    for (int i = 0; i < 4; ++i)
#pragma unroll
        for (int j = 0; j < CPW; ++j) {
            float4v z = {0.f, 0.f, 0.f, 0.f};
            acc[i][j] = z;
        }

    for (int kc = 0; kc < 128; kc += 32) {
        __syncthreads();                        // phase-1 done / prev chunk sW reads done
#pragma unroll
        for (int t = 0; t < 2; ++t) {
            const int cbase = (w * 2 + t) * 64;
            const int c = cbase + l;
            const int plane = c >> 9, rem = c & 511, sgw = rem >> 7, col = rem & 127;
            const ushort* srcp = plane ? LTlo : LThi;
            gload_lds16(&srcp[(size_t)col * 128 + kc + sgw * 8],
                        (char*)sW + (size_t)cbase * 16);
        }
        __syncthreads();

        const int chunk = kc >> 5;
        const int s8 = ((kc >> 3) + seg) & 7;
        short8v ah[4], al[4];
#pragma unroll
        for (int i = 0; i < 4; ++i) {
            const int row = wr * 64 + i * 16 + lr;
            const int slot = row ^ s8;
            ah[i] = *(const short8v*)&aggr[((size_t)(chunk * 2 + 0) * 512 + seg * 128 + slot) * 8];
            al[i] = *(const short8v*)&aggr[((size_t)(chunk * 2 + 1) * 512 + seg * 128 + slot) * 8];
        }
#pragma unroll
        for (int j = 0; j < CPW; ++j) {
            const int col = (wc * CPW + j) * 16 + lr;
            short8v bh = *(const short8v*)&sW[((size_t)0 * 512 + seg * 128 + col) * 8];
            short8v bl = *(const short8v*)&sW[((size_t)1 * 512 + seg * 128 + col) * 8];
#pragma unroll
            for (int i = 0; i < 4; ++i) {
                acc[i][j] = __builtin_amdgcn_mfma_f32_16x16x32_bf16(ah[i], bh, acc[i][j], 0, 0, 0);
                acc[i][j] = __builtin_amdgcn_mfma_f32_16x16x32_bf16(ah[i], bl, acc[i][j], 0, 0, 0);
                acc[i][j] = __builtin_amdgcn_mfma_f32_16x16x32_bf16(al[i], bh, acc[i][j], 0, 0, 0);
            }
        }
    }

    // epilogue -> left half hi/lo (stride 512)
#pragma unroll
    for (int i = 0; i < 4; ++i) {
#pragma unroll
        for (int j = 0; j < CPW; ++j) {
            const int gcol = (wc * CPW + j) * 16 + lr;
            const float bv = lb[gcol];
#pragma unroll
            for (int r = 0; r < 4; ++r) {
                const int grow = row0 + wr * 64 + i * 16 + seg * 4 + r;
                float v = fmaxf(acc[i][j][r] + bv, 0.f);
                ushort hi, lo;
                split_bf(v, hi, lo);
                Chi[(size_t)grow * 512 + gcol] = hi;
                Clo[(size_t)grow * 512 + gcol] = lo;
            }
        }
    }
}

// ============ f32 vector GEMM for input projection (K=32/64) -> hi/lo @ stride CS ============
template<int K>
__global__ __launch_bounds__(256)
void gemm_rt(const float* __restrict__ X, const float* __restrict__ W,
             const float* __restrict__ bias,
             ushort* __restrict__ Chi, ushort* __restrict__ Clo, int CS, int n)
{
    constexpr int TN = 128;
    constexpr int KC = 32;
    __shared__ float sXT[KC][128];
    __shared__ float sW[KC][TN];

    const int tid  = threadIdx.x;
    const int row0 = blockIdx.x * 128;
    const int rows = min(128, n - row0);
    if (rows <= 0) return;
    const int cg = tid % 16;
    const int rg = tid / 16;

    float acc[8][8] = {};

    for (int kc = 0; kc < K; kc += KC) {
        __syncthreads();
        for (int i = tid; i < KC * (TN / 4); i += 256) {
            int k = i / (TN / 4), c4 = i % (TN / 4);
            ((float4*)sW[k])[c4] = *(const float4*)&W[(size_t)(kc + k) * TN + c4 * 4];
        }
        for (int i = tid; i < (KC / 4) * 128; i += 256) {
            int r = i & 127, k4 = i >> 7;
            float4 v = {0.f, 0.f, 0.f, 0.f};
            if (r < rows) v = *(const float4*)&X[(size_t)(row0 + r) * K + kc + k4 * 4];
            sXT[k4 * 4 + 0][r] = v.x;
            sXT[k4 * 4 + 1][r] = v.y;
            sXT[k4 * 4 + 2][r] = v.z;
            sXT[k4 * 4 + 3][r] = v.w;
        }
        __syncthreads();
#pragma unroll 4
        for (int k = 0; k < KC; ++k) {
            float wv[8], xv[8];
            *(float4*)&wv[0] = *(const float4*)&sW[k][cg * 4];
            *(float4*)&wv[4] = *(const float4*)&sW[k][cg * 4 + 64];
            *(float4*)&xv[0] = *(const float4*)&sXT[k][rg * 4];
            *(float4*)&xv[4] = *(const float4*)&sXT[k][rg * 4 + 64];
#pragma unroll
            for (int i = 0; i < 8; ++i)
#pragma unroll
                for (int j = 0; j < 8; ++j)
                    acc[i][j] += xv[i] * wv[j];
        }
    }
#pragma unroll
    for (int i = 0; i < 8; ++i) {
        const int r = (i < 4) ? rg * 4 + i : 64 + rg * 4 + (i - 4);
        if (r < rows) {
#pragma unroll
            for (int half = 0; half < 2; ++half) {
                const int c = cg * 4 + half * 64;
                ushort4 h4, l4;
                ushort* hp = (ushort*)&h4; ushort* lp = (ushort*)&l4;
#pragma unroll
                for (int j = 0; j < 4; ++j) {
                    float v = fmaxf(acc[i][half * 4 + j] + bias[c + j], 0.f);
                    split_bf(v, hp[j], lp[j]);
                }
                *(ushort4*)&Chi[(size_t)(row0 + r) * CS + c] = h4;
                *(ushort4*)&Clo[(size_t)(row0 + r) * CS + c] = l4;
            }
        }
    }
}

// ============ weight transpose + split, both encoders ============
__global__ __launch_bounds__(256)
void tconv_all(const float* __restrict__ MWt, const float* __restrict__ MWg,
               const float* __restrict__ LWt, const float* __restrict__ LWg,
               ushort* __restrict__ WThi, ushort* __restrict__ WTlo,
               ushort* __restrict__ LThi, ushort* __restrict__ LTlo)
{
    int idx = blockIdx.x * 256 + threadIdx.x;
    if (idx < 2 * 98304) {
        int enc = idx / 98304, r2 = idx % 98304;
        int l = r2 >> 15, r = r2 & 32767;
        int row = r >> 7, c = r & 127;
        int k, col;
        if (row < 128) { k = row; col = c; } else { k = row - 128; col = 128 + c; }
        const float* src = enc ? MWg : MWt;
        ushort hi, lo;
        split_bf(src[r2], hi, lo);
        size_t o = (size_t)(enc * 3 + l) * 32768 + (size_t)col * 128 + k;
        WThi[o] = hi; WTlo[o] = lo;
    } else {
        int j = idx - 2 * 98304;
        if (j >= 2 * 49152) return;
        int enc = j / 49152, r2 = j % 49152;
        int l = r2 >> 14, r = r2 & 16383;
        int k = r >> 7, nn = r & 127;
        const float* src = enc ? LWg : LWt;
        ushort hi, lo;
        split_bf(src[r2], hi, lo);
        size_t o = (size_t)(enc * 3 + l) * 16384 + (size_t)nn * 128 + k;
        LThi[o] = hi; LTlo[o] = lo;
    }
}

// ============ CSR build (unified node space) ============
__global__ __launch_bounds__(256)
void hist_all(const int* __restrict__ tei, const int* __restrict__ gei,
              int et, int eg, int ntp, int* __restrict__ deg)
{
    int i = blockIdx.x * 256 + threadIdx.x;
    if (i < et) atomicAdd(&deg[tei[et + i]], 1);
    else if (i < et + eg) atomicAdd(&deg[gei[eg + (i - et)] + ntp], 1);
}

__global__ __launch_bounds__(256)
void scan_stage1(const int* __restrict__ in, int* __restrict__ excl,
                 int* __restrict__ partial, int n)
{
    const int tid = threadIdx.x;
    const int base = blockIdx.x * 1024 + tid * 4;
    int v[4];
    int s = 0;
#pragma unroll
    for (int i = 0; i < 4; ++i) {
        int t = (base + i < n) ? in[base + i] : 0;
        v[i] = s; s += t;
    }
    __shared__ int warpsum[4];
    const int lane = tid & 63, wid = tid >> 6;
    int pre = s;
#pragma unroll
    for (int off = 1; off < 64; off <<= 1) {
        int t = __shfl_up(pre, off);
        if (lane >= off) pre += t;
    }
    if (lane == 63) warpsum[wid] = pre;
    __syncthreads();
    int wo = 0;
    for (int w = 0; w < wid; ++w) wo += warpsum[w];
    const int thread_excl = wo + pre - s;
#pragma unroll
    for (int i = 0; i < 4; ++i)
        if (base + i < n) excl[base + i] = thread_excl + v[i];
    if (partial && tid == 255) partial[blockIdx.x] = wo + pre;
}

__global__ __launch_bounds__(256)
void scan_stage2(int* __restrict__ partial, int nb)
{
    __shared__ int tmp[256];
    const int tid = threadIdx.x;
    int v = (tid < nb) ? partial[tid] : 0;
    tmp[tid] = v;
    __syncthreads();
    for (int off = 1; off < 256; off <<= 1) {
        int t = (tid >= off) ? tmp[tid - off] : 0;
        __syncthreads();
        tmp[tid] += t;
        __syncthreads();
    }
    if (tid < nb) partial[tid] = tmp[tid] - v;
}

__global__ __launch_bounds__(256)
void scan_stage3(int* __restrict__ excl, const int* __restrict__ partial, int n)
{
    const int base = blockIdx.x * 1024 + threadIdx.x * 4;
    const int p = partial[blockIdx.x];
#pragma unroll
    for (int i = 0; i < 4; ++i)
        if (base + i < n) excl[base + i] += p;
}

__global__ __launch_bounds__(256)
void csr_fill_all(const int* __restrict__ tei, const int* __restrict__ gei,
                  int et, int eg, int ntp,
                  const int* __restrict__ rowptr, int* __restrict__ cursor,
                  int* __restrict__ csr_src)
{
    int e = blockIdx.x * 256 + threadIdx.x;
    int s, d;
    if (e < et) { s = tei[e]; d = tei[et + e]; }
    else if (e < et + eg) { int i = e - et; s = gei[i] + ntp; d = gei[eg + i] + ntp; }
    else return;
    int pos = atomicAdd(&cursor[d], 1);
    csr_src[rowptr[d] + pos] = s;
}

// ============ batch ranges via binary search (batch sorted) ============
__global__ __launch_bounds__(256)
void rpb_search(const int* __restrict__ batch_t, int nt,
                const int* __restrict__ batch_g, int ng, int* __restrict__ rpb)
{
    int t = blockIdx.x * 256 + threadIdx.x;
    if (t >= 2 * (NGRAPHS + 1)) return;
    const int enc = t / (NGRAPHS + 1);
    const int b = t % (NGRAPHS + 1);
    const int* batch = enc ? batch_g : batch_t;
    const int n = enc ? ng : nt;
    int lo = 0, hi = n;
    while (lo < hi) { int mid = (lo + hi) >> 1; if (batch[mid] < b) lo = mid + 1; else hi = mid; }
    rpb[t] = lo;
}

// ============ pooling (LEFT-half h, per-graph contiguous ranges) ============
__global__ __launch_bounds__(128)
void pool_mean(const ushort* __restrict__ U, const int* __restrict__ rpb,
               int ntp, float* __restrict__ fused)
{
    const int bid = blockIdx.x;
    const int enc = bid >> 10, b = bid & 1023;
    const int f = threadIdx.x;
    const int base_i = enc * (NGRAPHS + 1) + b;
    const int start = rpb[base_i];
    const int c = rpb[base_i + 1] - start;
    const int row0 = start + (enc ? ntp : 0);
    float acc = 0.f;
    for (int i = 0; i < c; ++i) {
        size_t o = (size_t)(row0 + i) * 512 + f;
        acc += bf2f(U[o]) + bf2f(U[o + 128]);
    }
    fused[(size_t)b * 256 + enc * 128 + f] = acc / fmaxf((float)c, 1.0f);
}

// ============ head ============
__global__ __launch_bounds__(128)
void head_kernel(const float* __restrict__ fused,
                 const float* __restrict__ muw, const float* __restrict__ mub,
                 const float* __restrict__ lvw, const float* __restrict__ lvb,
                 float* __restrict__ mu, float* __restrict__ lv)
{
    __shared__ float sf[2 * HIDDEN];
    const int b = blockIdx.x;
    const int t = threadIdx.x;
    sf[t] = fused[(size_t)b * 256 + t];
    sf[t + 128] = fused[(size_t)b * 256 + t + 128];
    __syncthreads();
    if (t < ZDIM) {
        float accm = mub[t], accl = lvb[t];
        for (int k = 0; k < 2 * HIDDEN; ++k) {
            float fv = sf[k];
            accm += fv * muw[(size_t)k * ZDIM + t];
            accl += fv * lvw[(size_t)k * ZDIM + t];
        }
        mu[(size_t)b * ZDIM + t] = accm;
        lv[(size_t)b * ZDIM + t] = accl;
    }
}

extern "C" void kernel_launch(void* const* d_in, const int* in_sizes, int n_in,
                              void* d_out, int out_size, void* d_ws, size_t ws_size,
                              hipStream_t stream)
{
    const float* tree_x   = (const float*)d_in[0];
    const int*   tree_ei  = (const int*)d_in[1];
    const float* graph_x  = (const float*)d_in[2];
    const int*   graph_ei = (const int*)d_in[3];
    const int*   batch_t  = (const int*)d_in[4];
    const int*   batch_g  = (const int*)d_in[5];
    const float* t_proj_w = (const float*)d_in[6];
    const float* t_proj_b = (const float*)d_in[7];
    const float* t_msg_w  = (const float*)d_in[8];
    const float* t_msg_b  = (const float*)d_in[9];
    const float* t_lin_w  = (const float*)d_in[10];
    const float* t_lin_b  = (const float*)d_in[11];
    const float* g_proj_w = (const float*)d_in[12];
    const float* g_proj_b = (const float*)d_in[13];
    const float* g_msg_w  = (const float*)d_in[14];
    const float* g_msg_b  = (const float*)d_in[15];
    const float* g_lin_w  = (const float*)d_in[16];
    const float* g_lin_b  = (const float*)d_in[17];
    const float* mu_w     = (const float*)d_in[18];
    const float* mu_b     = (const float*)d_in[19];
    const float* lv_w     = (const float*)d_in[20];
    const float* lv_b     = (const float*)d_in[21];

    const int n_tree  = in_sizes[0] / 64;
    const int e_tree  = in_sizes[1] / 2;
    const int n_graph = in_sizes[2] / 32;
    const int e_graph = in_sizes[3] / 2;
    const int E_tot   = e_tree + e_graph;

    const int ntp  = ((n_tree + 127) / 128) * 128;
    const int npg  = ((n_graph + 127) / 128) * 128;
    const int NTOT = ntp + npg;
    const int GB   = NTOT / 128;

    float* out    = (float*)d_out;
    float* mu_out = out;
    float* lv_out = out + (size_t)NGRAPHS * ZDIM;
    float* fused  = out + (size_t)2 * NGRAPHS * ZDIM;

    // ---- workspace carve ----
    char* base = (char*)d_ws;
    float*  buf  = (float*)base;  base += (size_t)NTOT * 256 * sizeof(float);
    ushort* U    = (ushort*)buf;
    ushort* WThi = (ushort*)base; base += (size_t)6 * 32768 * sizeof(ushort);
    ushort* WTlo = (ushort*)base; base += (size_t)6 * 32768 * sizeof(ushort);
    ushort* LThi = (ushort*)base; base += (size_t)6 * 16384 * sizeof(ushort);
    ushort* LTlo = (ushort*)base; base += (size_t)6 * 16384 * sizeof(ushort);
    int* deg     = (int*)base;    base += (size_t)NTOT * sizeof(int);
    int* cursor  = (int*)base;    base += (size_t)NTOT * sizeof(int);
    int* rowptr  = (int*)base;    base += (size_t)NTOT * sizeof(int);
    int* csr_src = (int*)base;    base += (size_t)E_tot * sizeof(int);
    int* partial = (int*)base;    base += 256 * sizeof(int);
    int* rpb     = (int*)base;

    const int nb = (NTOT + 1023) / 1024;

    // ---- CSR build (unified) ----
    hipMemsetAsync(deg, 0, (size_t)2 * NTOT * sizeof(int), stream);
    hist_all<<<(E_tot + 255) / 256, 256, 0, stream>>>(tree_ei, graph_ei, e_tree, e_graph, ntp, deg);
    scan_stage1<<<nb, 256, 0, stream>>>(deg, rowptr, partial, NTOT);
    scan_stage2<<<1, 256, 0, stream>>>(partial, nb);
    scan_stage3<<<nb, 256, 0, stream>>>(rowptr, partial, NTOT);
    csr_fill_all<<<(E_tot + 255) / 256, 256, 0, stream>>>(tree_ei, graph_ei, e_tree, e_graph,
                                                          ntp, rowptr, cursor, csr_src);
    rpb_search<<<(2 * (NGRAPHS + 1) + 255) / 256, 256, 0, stream>>>(batch_t, n_tree,
                                                                    batch_g, n_graph, rpb);
    tconv_all<<<(2 * 98304 + 2 * 49152 + 255) / 256, 256, 0, stream>>>(
        t_msg_w, g_msg_w, t_lin_w, g_lin_w, WThi, WTlo, LThi, LTlo);

    // ---- input projections -> LEFT-half h hi/lo ----
    gemm_rt<64><<<(n_tree + 127) / 128, 256, 0, stream>>>(
        tree_x, t_proj_w, t_proj_b, U, U + 128, 512, n_tree);
    gemm_rt<32><<<(n_graph + 127) / 128, 256, 0, stream>>>(
        graph_x, g_proj_w, g_proj_b,
        U + (size_t)ntp * 512, U + 128 + (size_t)ntp * 512, 512, n_graph);

    // ---- fused layer loop ----
    for (int l = 0; l < NLAYERS; ++l) {
        // AB = h @ [Wtop|Wbot] : LEFT-half X -> full-row f32 (in place per block)
        gemm_mfma<256><<<GB, 512, 0, stream>>>(
            U, U + 128, 512,
            WThi + (size_t)l * 32768, WTlo + (size_t)l * 32768,
            WThi + (size_t)(3 + l) * 32768, WTlo + (size_t)(3 + l) * 32768,
            buf, ntp);
        // h' = relu(gather(AB) @ lin + b) -> LEFT-half hi/lo (aggr never touches HBM)
        gather_lin<<<GB, 512, 81920, stream>>>(
            buf, t_msg_b + (size_t)l * HIDDEN, g_msg_b + (size_t)l * HIDDEN,
            rowptr, deg, csr_src,
            LThi + (size_t)l * 16384, LTlo + (size_t)l * 16384,
            LThi + (size_t)(3 + l) * 16384, LTlo + (size_t)(3 + l) * 16384,
            t_lin_b + (size_t)l * HIDDEN, g_lin_b + (size_t)l * HIDDEN,
            U, U + 128, ntp);
    }

    pool_mean<<<2 * NGRAPHS, 128, 0, stream>>>(U, rpb, ntp, fused);
    head_kernel<<<NGRAPHS, 128, 0, stream>>>(fused, mu_w, mu_b, lv_w, lv_b, mu_out, lv_out);
}